// Round 1
// baseline (412.812 us; speedup 1.0000x reference)
//
#include <hip/hip_runtime.h>
#include <cstdint>
#include <cstddef>

#define B_ 4
#define TQ_ 1024
#define TKV_ 1024
#define D_ 1024
#define H_ 16
#define HD_ 64

typedef __bf16 bf16_t;
typedef bf16_t bf16x4 __attribute__((ext_vector_type(4)));
typedef bf16_t bf16x8 __attribute__((ext_vector_type(8)));
typedef float f32x4 __attribute__((ext_vector_type(4)));

__device__ __forceinline__ bf16_t to_bf16(float f) {
  uint32_t u = __builtin_bit_cast(uint32_t, f);
  u += 0x7fffu + ((u >> 16) & 1u);
  uint16_t h = (uint16_t)(u >> 16);
  return __builtin_bit_cast(bf16_t, h);
}
__device__ __forceinline__ float bf2f(bf16_t b) {
  uint32_t u = ((uint32_t)__builtin_bit_cast(uint16_t, b)) << 16;
  return __builtin_bit_cast(float, u);
}
__device__ __forceinline__ void gload_lds16(const void* g, void* l) {
  __builtin_amdgcn_global_load_lds((const __attribute__((address_space(1))) void*)g,
                                   (__attribute__((address_space(3))) void*)l, 16, 0, 0);
}

// ---------------- elementwise fp32 -> bf16 (vec4) ----------------
__global__ __launch_bounds__(256) void k_f2b(const float* __restrict__ in,
                                             bf16_t* __restrict__ out, int n4) {
  int i = blockIdx.x * 256 + threadIdx.x;
  if (i >= n4) return;
  float4 v = ((const float4*)in)[i];
  bf16x4 o = {to_bf16(v.x), to_bf16(v.y), to_bf16(v.z), to_bf16(v.w)};
  *(bf16x4*)(out + (size_t)i * 4) = o;
}

// ---------------- transpose + convert: in fp32 (R,C) -> out bf16 (C,R) ----------------
__global__ __launch_bounds__(256) void k_trb(const float* __restrict__ in,
                                             bf16_t* __restrict__ out, int R, int C) {
  __shared__ float tile[32][33];
  int tx = threadIdx.x & 31, ty = threadIdx.x >> 5;
  int c0 = blockIdx.x * 32, r0 = blockIdx.y * 32;
#pragma unroll
  for (int i = 0; i < 4; i++)
    tile[ty + i * 8][tx] = in[(size_t)(r0 + ty + i * 8) * C + c0 + tx];
  __syncthreads();
#pragma unroll
  for (int i = 0; i < 4; i++) {
    int rr = ty + i * 8;
    out[(size_t)(c0 + rr) * R + r0 + tx] = to_bf16(tile[tx][rr]);
  }
}

// ---------------- bf16 GEMM: C[M,N] = A[M,K] * Bt[N,K]^T  (m97 structure) ----------------
template <bool BF16OUT>
__global__ __launch_bounds__(256, 2) void k_gemm(const bf16_t* __restrict__ A,
                                                 const bf16_t* __restrict__ Bt,
                                                 void* __restrict__ Cv, int N, int K) {
  __shared__ bf16_t As[128 * 32];
  __shared__ bf16_t Bs[128 * 32];
  const int tid = threadIdx.x;
  const int wave = tid >> 6, lane = tid & 63;
  const int ln = lane & 15, lq = lane >> 4;
  const int m0 = blockIdx.y * 128, n0 = blockIdx.x * 128;
  const int wm = (wave >> 1) * 64, wn = (wave & 1) * 64;
  f32x4 acc[4][4];
#pragma unroll
  for (int i = 0; i < 4; i++)
#pragma unroll
    for (int j = 0; j < 4; j++) acc[i][j] = (f32x4){0.f, 0.f, 0.f, 0.f};

  for (int k0 = 0; k0 < K; k0 += 32) {
#pragma unroll
    for (int rnd = 0; rnd < 2; rnd++) {
      int c = rnd * 256 + tid;
      int row = c >> 2, col = (c & 3) * 8;
      int ldsoff = (rnd * 256 + wave * 64) * 16;  // wave-uniform; HW adds lane*16
      gload_lds16(A + (size_t)(m0 + row) * K + k0 + col, (char*)As + ldsoff);
      gload_lds16(Bt + (size_t)(n0 + row) * K + k0 + col, (char*)Bs + ldsoff);
    }
    asm volatile("s_waitcnt vmcnt(0)" ::: "memory");
    __syncthreads();
    bf16x8 af[4], bfr[4];
#pragma unroll
    for (int i = 0; i < 4; i++) {
      af[i] = *(const bf16x8*)(As + (wm + i * 16 + ln) * 32 + lq * 8);
      bfr[i] = *(const bf16x8*)(Bs + (wn + i * 16 + ln) * 32 + lq * 8);
    }
#pragma unroll
    for (int i = 0; i < 4; i++)
#pragma unroll
      for (int j = 0; j < 4; j++)
        acc[i][j] = __builtin_amdgcn_mfma_f32_16x16x32_bf16(af[i], bfr[j], acc[i][j], 0, 0, 0);
    __syncthreads();
  }
#pragma unroll
  for (int i = 0; i < 4; i++)
#pragma unroll
    for (int j = 0; j < 4; j++)
#pragma unroll
      for (int r = 0; r < 4; r++) {
        int row = m0 + wm + i * 16 + lq * 4 + r;
        int col = n0 + wn + j * 16 + ln;
        if (BF16OUT)
          ((bf16_t*)Cv)[(size_t)row * N + col] = to_bf16(acc[i][j][r]);
        else
          ((float*)Cv)[(size_t)row * N + col] = acc[i][j][r];
      }
}

// ---------------- per-head RMSNorm of q1/q2 (scale 1/8 folded in) ----------------
__global__ __launch_bounds__(256) void k_rms_q(const bf16_t* __restrict__ q12,
                                               const float* __restrict__ qn1,
                                               const float* __restrict__ qn2,
                                               bf16_t* __restrict__ q1h,
                                               bf16_t* __restrict__ q2h) {
  int wave = threadIdx.x >> 6, lane = threadIdx.x & 63;
  int g = blockIdx.x * 4 + wave;          // [0, 4096*32)
  int row = g >> 5, rem = g & 31;
  int half = rem >> 4, h = rem & 15;
  float v = bf2f(q12[(size_t)row * 2048 + half * 1024 + h * 64 + lane]);
  float ss = v * v;
#pragma unroll
  for (int m = 1; m < 64; m <<= 1) ss += __shfl_xor(ss, m, 64);
  float rr = rsqrtf(ss * (1.f / 64.f) + 1e-5f);
  float w = (half ? qn2 : qn1)[lane];
  int b = row >> 10, t = row & 1023;
  (half ? q2h : q1h)[(((size_t)(b * 16 + h)) * 1024 + t) * 64 + lane] =
      to_bf16(v * rr * w * 0.125f);
}

// ---------------- per-head RMSNorm of k1/k2 + v passthrough ----------------
__global__ __launch_bounds__(256) void k_rms_kv(const bf16_t* __restrict__ kv3,
                                                const float* __restrict__ kn1,
                                                const float* __restrict__ kn2,
                                                bf16_t* __restrict__ k1h,
                                                bf16_t* __restrict__ k2h,
                                                bf16_t* __restrict__ vh) {
  int wave = threadIdx.x >> 6, lane = threadIdx.x & 63;
  int g = blockIdx.x * 4 + wave;          // [0, 4096*48)
  int row = g / 48, rem = g % 48;
  int part = rem >> 4, h = rem & 15;
  float v = bf2f(kv3[(size_t)row * 3072 + part * 1024 + h * 64 + lane]);
  int b = row >> 10, t = row & 1023;
  size_t oidx = (((size_t)(b * 16 + h)) * 1024 + t) * 64 + lane;
  if (part == 2) {
    vh[oidx] = to_bf16(v);
  } else {
    float ss = v * v;
#pragma unroll
    for (int m = 1; m < 64; m <<= 1) ss += __shfl_xor(ss, m, 64);
    float rr = rsqrtf(ss * (1.f / 64.f) + 1e-5f);
    float w = (part ? kn2 : kn1)[lane];
    (part ? k2h : k1h)[oidx] = to_bf16(v * rr * w);
  }
}

// ---------------- flash attention (non-causal), one stream per launch ----------------
// grid (TQ/128, B*H); block 256 (4 waves x 32 q-rows). Q pre-scaled by 1/8.
__global__ __launch_bounds__(256) void k_attn(const bf16_t* __restrict__ qh,
                                              const bf16_t* __restrict__ kh,
                                              const bf16_t* __restrict__ vhd,
                                              float* __restrict__ yo) {
  __shared__ bf16_t Ks[64][72];   // K chunk, row-major, +8 pad
  __shared__ bf16_t Vt[64][72];   // V chunk transposed [d][kv], +8 pad
  __shared__ bf16_t Ps[4][16][72];
  const int tid = threadIdx.x;
  const int wave = tid >> 6, lane = tid & 63;
  const int ln = lane & 15, lq = lane >> 4;
  const int bh = blockIdx.y;
  const int q0 = blockIdx.x * 128 + wave * 32;
  const bf16_t* qb = qh + (size_t)bh * TQ_ * HD_;
  const bf16_t* kb = kh + (size_t)bh * TKV_ * HD_;
  const bf16_t* vb = vhd + (size_t)bh * TKV_ * HD_;

  bf16x8 qf[2][2];
#pragma unroll
  for (int mt = 0; mt < 2; mt++)
#pragma unroll
    for (int ks = 0; ks < 2; ks++)
      qf[mt][ks] = *(const bf16x8*)(qb + (size_t)(q0 + mt * 16 + ln) * HD_ + ks * 32 + lq * 8);

  f32x4 O[2][4];
  float ms[2][4], ls[2][4];
#pragma unroll
  for (int mt = 0; mt < 2; mt++) {
#pragma unroll
    for (int nt = 0; nt < 4; nt++) O[mt][nt] = (f32x4){0.f, 0.f, 0.f, 0.f};
#pragma unroll
    for (int r = 0; r < 4; r++) { ms[mt][r] = -1e30f; ls[mt][r] = 0.f; }
  }

  for (int kv0 = 0; kv0 < TKV_; kv0 += 64) {
    __syncthreads();
    // stage K chunk (coalesced 16B per thread, 2 rounds)
#pragma unroll
    for (int rnd = 0; rnd < 2; rnd++) {
      int c = rnd * 256 + tid;
      bf16x8 d = *(const bf16x8*)(kb + (size_t)(kv0 + (c >> 3)) * HD_ + (c & 7) * 8);
      *(bf16x8*)(&Ks[c >> 3][(c & 7) * 8]) = d;
    }
    // stage V transposed
    {
      int r = tid >> 2, d0 = (tid & 3) * 16;
      bf16x8 v0 = *(const bf16x8*)(vb + (size_t)(kv0 + r) * HD_ + d0);
      bf16x8 v1 = *(const bf16x8*)(vb + (size_t)(kv0 + r) * HD_ + d0 + 8);
#pragma unroll
      for (int j = 0; j < 8; j++) {
        Vt[d0 + j][r] = v0[j];
        Vt[d0 + 8 + j][r] = v1[j];
      }
    }
    __syncthreads();

    bf16x8 vf[4][2];
#pragma unroll
    for (int nt = 0; nt < 4; nt++)
#pragma unroll
      for (int ks = 0; ks < 2; ks++)
        vf[nt][ks] = *(const bf16x8*)(&Vt[nt * 16 + ln][ks * 32 + lq * 8]);

#pragma unroll
    for (int mt = 0; mt < 2; mt++) {
      f32x4 s[4];
#pragma unroll
      for (int nt = 0; nt < 4; nt++) s[nt] = (f32x4){0.f, 0.f, 0.f, 0.f};
#pragma unroll
      for (int ks = 0; ks < 2; ks++)
#pragma unroll
        for (int nt = 0; nt < 4; nt++) {
          bf16x8 kf = *(const bf16x8*)(&Ks[nt * 16 + ln][ks * 32 + lq * 8]);
          s[nt] = __builtin_amdgcn_mfma_f32_16x16x32_bf16(qf[mt][ks], kf, s[nt], 0, 0, 0);
        }
      // online softmax (rows = lq*4+r, cols across ln and nt)
      float rowmax[4], rowsum[4];
#pragma unroll
      for (int r = 0; r < 4; r++)
        rowmax[r] = fmaxf(fmaxf(s[0][r], s[1][r]), fmaxf(s[2][r], s[3][r]));
#pragma unroll
      for (int m = 1; m < 16; m <<= 1)
#pragma unroll
        for (int r = 0; r < 4; r++)
          rowmax[r] = fmaxf(rowmax[r], __shfl_xor(rowmax[r], m, 64));
#pragma unroll
      for (int r = 0; r < 4; r++) {
        float mnew = fmaxf(ms[mt][r], rowmax[r]);
        float alpha = __expf(ms[mt][r] - mnew);
        ms[mt][r] = mnew;
        float rs = 0.f;
#pragma unroll
        for (int nt = 0; nt < 4; nt++) {
          float p = __expf(s[nt][r] - mnew);
          s[nt][r] = p;
          rs += p;
        }
        rowsum[r] = rs;
        ls[mt][r] *= alpha;
#pragma unroll
        for (int nt = 0; nt < 4; nt++) O[mt][nt][r] *= alpha;
      }
#pragma unroll
      for (int m = 1; m < 16; m <<= 1)
#pragma unroll
        for (int r = 0; r < 4; r++) rowsum[r] += __shfl_xor(rowsum[r], m, 64);
#pragma unroll
      for (int r = 0; r < 4; r++) ls[mt][r] += rowsum[r];
      // P: C-layout -> LDS -> A-layout
#pragma unroll
      for (int nt = 0; nt < 4; nt++)
#pragma unroll
        for (int r = 0; r < 4; r++)
          Ps[wave][lq * 4 + r][nt * 16 + ln] = to_bf16(s[nt][r]);
      asm volatile("s_waitcnt lgkmcnt(0)" ::: "memory");
      bf16x8 pf[2];
#pragma unroll
      for (int ks = 0; ks < 2; ks++)
        pf[ks] = *(const bf16x8*)(&Ps[wave][ln][ks * 32 + lq * 8]);
#pragma unroll
      for (int ks = 0; ks < 2; ks++)
#pragma unroll
        for (int nt = 0; nt < 4; nt++)
          O[mt][nt] = __builtin_amdgcn_mfma_f32_16x16x32_bf16(pf[ks], vf[nt][ks], O[mt][nt], 0, 0, 0);
    }
  }
#pragma unroll
  for (int mt = 0; mt < 2; mt++)
#pragma unroll
    for (int r = 0; r < 4; r++) {
      float inv = 1.f / ls[mt][r];
      int qr = q0 + mt * 16 + lq * 4 + r;
#pragma unroll
      for (int nt = 0; nt < 4; nt++)
        yo[((size_t)bh * TQ_ + qr) * HD_ + nt * 16 + ln] = O[mt][nt][r] * inv;
    }
}

// ---------------- GroupNorm stats per (b,h): y = y1 - c*y2 ----------------
__global__ __launch_bounds__(1024) void k_gn_stats(const float* __restrict__ y1,
                                                   const float* __restrict__ y2,
                                                   const float* __restrict__ lmb,
                                                   float* __restrict__ stats) {
  int bh = blockIdx.x;
  int h = bh & 15;
  float c = log1pf(__expf(lmb[h]));
  const float* p1 = y1 + (size_t)bh * 65536;
  const float* p2 = y2 + (size_t)bh * 65536;
  float s = 0.f, ss = 0.f;
  for (int i = threadIdx.x; i < 65536; i += 1024) {
    float v = p1[i] - c * p2[i];
    s += v;
    ss += v * v;
  }
#pragma unroll
  for (int m = 1; m < 64; m <<= 1) {
    s += __shfl_xor(s, m, 64);
    ss += __shfl_xor(ss, m, 64);
  }
  __shared__ float red[32];
  int wv = threadIdx.x >> 6;
  if ((threadIdx.x & 63) == 0) { red[wv] = s; red[16 + wv] = ss; }
  __syncthreads();
  if (threadIdx.x == 0) {
    float S = 0.f, SS = 0.f;
    for (int i = 0; i < 16; i++) { S += red[i]; SS += red[16 + i]; }
    float mean = S * (1.f / 65536.f);
    float var = SS * (1.f / 65536.f) - mean * mean;
    stats[bh * 2] = mean;
    stats[bh * 2 + 1] = rsqrtf(var + 1e-5f);
  }
}

// ---------------- GroupNorm apply + transpose to (B,TQ,D) bf16 ----------------
__global__ __launch_bounds__(256) void k_gn_apply(const float* __restrict__ y1,
                                                  const float* __restrict__ y2,
                                                  const float* __restrict__ stats,
                                                  const float* __restrict__ lmb,
                                                  const float* __restrict__ gw,
                                                  const float* __restrict__ gb,
                                                  bf16_t* __restrict__ yn) {
  int idx = blockIdx.x * 256 + threadIdx.x;  // vec4 id over 4M elems
  int i = idx * 4;
  int bh = i >> 16;
  int h = bh & 15, b = bh >> 4;
  float c = log1pf(__expf(lmb[h]));
  float mean = stats[bh * 2], rstd = stats[bh * 2 + 1];
  float4 a = *(const float4*)(y1 + i);
  float4 w2 = *(const float4*)(y2 + i);
  int rem = i & 65535;
  int t = rem >> 6, d = rem & 63;
  float4 gwv = *(const float4*)(gw + h * 64 + d);
  float4 gbv = *(const float4*)(gb + h * 64 + d);
  float o0 = ((a.x - c * w2.x) - mean) * rstd * gwv.x + gbv.x;
  float o1 = ((a.y - c * w2.y) - mean) * rstd * gwv.y + gbv.y;
  float o2 = ((a.z - c * w2.z) - mean) * rstd * gwv.z + gbv.z;
  float o3 = ((a.w - c * w2.w) - mean) * rstd * gwv.w + gbv.w;
  bf16x4 o = {to_bf16(o0), to_bf16(o1), to_bf16(o2), to_bf16(o3)};
  *(bf16x4*)(yn + ((size_t)(b * 1024 + t)) * 1024 + h * 64 + d) = o;
}

extern "C" void kernel_launch(void* const* d_in, const int* in_sizes, int n_in,
                              void* d_out, int out_size, void* d_ws, size_t ws_size,
                              hipStream_t stream) {
  const float* x_q = (const float*)d_in[0];
  const float* x_kv = (const float*)d_in[1];
  const float* Wq = (const float*)d_in[2];
  const float* Wkv = (const float*)d_in[3];
  const float* Wc = (const float*)d_in[4];
  const float* qn1 = (const float*)d_in[5];
  const float* kn1 = (const float*)d_in[6];
  const float* qn2 = (const float*)d_in[7];
  const float* kn2 = (const float*)d_in[8];
  const float* gn_w = (const float*)d_in[9];
  const float* gn_b = (const float*)d_in[10];
  const float* lmb = (const float*)d_in[11];

  const size_t MB = (size_t)1 << 20;
  char* ws = (char*)d_ws;
  bf16_t* xq_bf = (bf16_t*)(ws + 0 * MB);    // 8 MB
  bf16_t* xkv_bf = (bf16_t*)(ws + 8 * MB);   // 8 MB
  bf16_t* Wqt = (bf16_t*)(ws + 16 * MB);     // 4 MB  (2048x1024)
  bf16_t* Wkvt = (bf16_t*)(ws + 20 * MB);    // 6 MB  (3072x1024)
  bf16_t* Wct = (bf16_t*)(ws + 26 * MB);     // 2 MB  (1024x1024)
  bf16_t* q12 = (bf16_t*)(ws + 28 * MB);     // 16 MB (4096x2048)
  bf16_t* kv3 = (bf16_t*)(ws + 44 * MB);     // 24 MB (4096x3072)
  bf16_t* q1h = (bf16_t*)(ws + 68 * MB);     // 8 MB  (B,H,TQ,HD)
  bf16_t* q2h = (bf16_t*)(ws + 76 * MB);
  bf16_t* k1h = (bf16_t*)(ws + 84 * MB);
  bf16_t* k2h = (bf16_t*)(ws + 92 * MB);
  bf16_t* vh = (bf16_t*)(ws + 100 * MB);
  float* y1 = (float*)(ws + 108 * MB);       // 16 MB fp32
  float* y2 = (float*)(ws + 124 * MB);
  bf16_t* yn = (bf16_t*)(ws + 140 * MB);     // 8 MB
  float* stats = (float*)(ws + 148 * MB);    // 128 floats

  // convert activations
  k_f2b<<<4096, 256, 0, stream>>>(x_q, xq_bf, 1048576);
  k_f2b<<<4096, 256, 0, stream>>>(x_kv, xkv_bf, 1048576);
  // transpose+convert weights to (N,K)
  k_trb<<<dim3(64, 32), 256, 0, stream>>>(Wq, Wqt, 1024, 2048);
  k_trb<<<dim3(96, 32), 256, 0, stream>>>(Wkv, Wkvt, 1024, 3072);
  k_trb<<<dim3(32, 32), 256, 0, stream>>>(Wc, Wct, 1024, 1024);
  // projections
  k_gemm<true><<<dim3(16, 32), 256, 0, stream>>>(xq_bf, Wqt, q12, 2048, 1024);
  k_gemm<true><<<dim3(24, 32), 256, 0, stream>>>(xkv_bf, Wkvt, kv3, 3072, 1024);
  // per-head RMSNorm + head layout
  k_rms_q<<<32768, 256, 0, stream>>>(q12, qn1, qn2, q1h, q2h);
  k_rms_kv<<<49152, 256, 0, stream>>>(kv3, kn1, kn2, k1h, k2h, vh);
  // dual attention
  k_attn<<<dim3(8, 64), 256, 0, stream>>>(q1h, k1h, vh, y1);
  k_attn<<<dim3(8, 64), 256, 0, stream>>>(q2h, k2h, vh, y2);
  // groupnorm
  k_gn_stats<<<64, 1024, 0, stream>>>(y1, y2, lmb, stats);
  k_gn_apply<<<4096, 256, 0, stream>>>(y1, y2, stats, lmb, gn_w, gn_b, yn);
  // output projection (fp32 out)
  k_gemm<false><<<dim3(8, 32), 256, 0, stream>>>(yn, Wct, d_out, 1024, 1024);
}

// Round 2
// 338.363 us; speedup vs baseline: 1.2200x; 1.2200x over previous
//
#include <hip/hip_runtime.h>
#include <cstdint>
#include <cstddef>

#define B_ 4
#define TQ_ 1024
#define TKV_ 1024
#define D_ 1024
#define H_ 16
#define HD_ 64

typedef __bf16 bf16_t;
typedef bf16_t bf16x4 __attribute__((ext_vector_type(4)));
typedef bf16_t bf16x8 __attribute__((ext_vector_type(8)));
typedef float f32x4 __attribute__((ext_vector_type(4)));

__device__ __forceinline__ bf16_t to_bf16(float f) {
  uint32_t u = __builtin_bit_cast(uint32_t, f);
  u += 0x7fffu + ((u >> 16) & 1u);
  uint16_t h = (uint16_t)(u >> 16);
  return __builtin_bit_cast(bf16_t, h);
}
__device__ __forceinline__ float bf2f(bf16_t b) {
  uint32_t u = ((uint32_t)__builtin_bit_cast(uint16_t, b)) << 16;
  return __builtin_bit_cast(float, u);
}
__device__ __forceinline__ void gload_lds16(const void* g, void* l) {
  __builtin_amdgcn_global_load_lds((const __attribute__((address_space(1))) void*)g,
                                   (__attribute__((address_space(3))) void*)l, 16, 0, 0);
}

// ---------------- elementwise fp32 -> bf16 (vec4) ----------------
__global__ __launch_bounds__(256) void k_f2b(const float* __restrict__ in,
                                             bf16_t* __restrict__ out, int n4) {
  int i = blockIdx.x * 256 + threadIdx.x;
  if (i >= n4) return;
  float4 v = ((const float4*)in)[i];
  bf16x4 o = {to_bf16(v.x), to_bf16(v.y), to_bf16(v.z), to_bf16(v.w)};
  *(bf16x4*)(out + (size_t)i * 4) = o;
}

// ---------------- transpose + convert: in fp32 (R,C) -> out bf16 (C,R) ----------------
__global__ __launch_bounds__(256) void k_trb(const float* __restrict__ in,
                                             bf16_t* __restrict__ out, int R, int C) {
  __shared__ float tile[32][33];
  int tx = threadIdx.x & 31, ty = threadIdx.x >> 5;
  int c0 = blockIdx.x * 32, r0 = blockIdx.y * 32;
#pragma unroll
  for (int i = 0; i < 4; i++)
    tile[ty + i * 8][tx] = in[(size_t)(r0 + ty + i * 8) * C + c0 + tx];
  __syncthreads();
#pragma unroll
  for (int i = 0; i < 4; i++) {
    int rr = ty + i * 8;
    out[(size_t)(c0 + rr) * R + r0 + tx] = to_bf16(tile[tx][rr]);
  }
}

// ---------------- per-head bf16 transpose: vh[bh][t][d] -> vt[bh][d][t] ----------------
__global__ __launch_bounds__(256) void k_trv(const bf16_t* __restrict__ in,
                                             bf16_t* __restrict__ out) {
  __shared__ bf16_t tile[64][65];
  int bh = blockIdx.y;
  int t0 = blockIdx.x * 64;
  const bf16_t* ib = in + (size_t)bh * 65536;
  bf16_t* ob = out + (size_t)bh * 65536;
  int r = threadIdx.x >> 2, c8 = (threadIdx.x & 3) * 16;
  bf16x8 a = *(const bf16x8*)(ib + (size_t)(t0 + r) * 64 + c8);
  bf16x8 b = *(const bf16x8*)(ib + (size_t)(t0 + r) * 64 + c8 + 8);
#pragma unroll
  for (int j = 0; j < 8; j++) {
    tile[c8 + j][r] = a[j];
    tile[c8 + 8 + j][r] = b[j];
  }
  __syncthreads();
  int d = threadIdx.x >> 2, tt = (threadIdx.x & 3) * 16;
  bf16x8 o0, o1;
#pragma unroll
  for (int j = 0; j < 8; j++) {
    o0[j] = tile[d][tt + j];
    o1[j] = tile[d][tt + 8 + j];
  }
  *(bf16x8*)(ob + (size_t)d * 1024 + t0 + tt) = o0;
  *(bf16x8*)(ob + (size_t)d * 1024 + t0 + tt + 8) = o1;
}

// ---------------- bf16 GEMM: C[M,N] = A[M,K] * Bt[N,K]^T  (m97 structure) ----------------
template <bool BF16OUT>
__global__ __launch_bounds__(256, 2) void k_gemm(const bf16_t* __restrict__ A,
                                                 const bf16_t* __restrict__ Bt,
                                                 void* __restrict__ Cv, int N, int K) {
  __shared__ bf16_t As[128 * 32];
  __shared__ bf16_t Bs[128 * 32];
  const int tid = threadIdx.x;
  const int wave = tid >> 6, lane = tid & 63;
  const int ln = lane & 15, lq = lane >> 4;
  const int m0 = blockIdx.y * 128, n0 = blockIdx.x * 128;
  const int wm = (wave >> 1) * 64, wn = (wave & 1) * 64;
  f32x4 acc[4][4];
#pragma unroll
  for (int i = 0; i < 4; i++)
#pragma unroll
    for (int j = 0; j < 4; j++) acc[i][j] = (f32x4){0.f, 0.f, 0.f, 0.f};

  for (int k0 = 0; k0 < K; k0 += 32) {
#pragma unroll
    for (int rnd = 0; rnd < 2; rnd++) {
      int c = rnd * 256 + tid;
      int row = c >> 2, col = (c & 3) * 8;
      int ldsoff = (rnd * 256 + wave * 64) * 16;
      gload_lds16(A + (size_t)(m0 + row) * K + k0 + col, (char*)As + ldsoff);
      gload_lds16(Bt + (size_t)(n0 + row) * K + k0 + col, (char*)Bs + ldsoff);
    }
    asm volatile("s_waitcnt vmcnt(0)" ::: "memory");
    __syncthreads();
    bf16x8 af[4], bfr[4];
#pragma unroll
    for (int i = 0; i < 4; i++) {
      af[i] = *(const bf16x8*)(As + (wm + i * 16 + ln) * 32 + lq * 8);
      bfr[i] = *(const bf16x8*)(Bs + (wn + i * 16 + ln) * 32 + lq * 8);
    }
#pragma unroll
    for (int i = 0; i < 4; i++)
#pragma unroll
      for (int j = 0; j < 4; j++)
        acc[i][j] = __builtin_amdgcn_mfma_f32_16x16x32_bf16(af[i], bfr[j], acc[i][j], 0, 0, 0);
    __syncthreads();
  }
#pragma unroll
  for (int i = 0; i < 4; i++)
#pragma unroll
    for (int j = 0; j < 4; j++)
#pragma unroll
      for (int r = 0; r < 4; r++) {
        int row = m0 + wm + i * 16 + lq * 4 + r;
        int col = n0 + wn + j * 16 + ln;
        if (BF16OUT)
          ((bf16_t*)Cv)[(size_t)row * N + col] = to_bf16(acc[i][j][r]);
        else
          ((float*)Cv)[(size_t)row * N + col] = acc[i][j][r];
      }
}

// ---------------- per-head RMSNorm of q1/q2 (scale 1/8 folded in) ----------------
__global__ __launch_bounds__(256) void k_rms_q(const bf16_t* __restrict__ q12,
                                               const float* __restrict__ qn1,
                                               const float* __restrict__ qn2,
                                               bf16_t* __restrict__ q1h,
                                               bf16_t* __restrict__ q2h) {
  int wave = threadIdx.x >> 6, lane = threadIdx.x & 63;
  int g = blockIdx.x * 4 + wave;
  int row = g >> 5, rem = g & 31;
  int half = rem >> 4, h = rem & 15;
  float v = bf2f(q12[(size_t)row * 2048 + half * 1024 + h * 64 + lane]);
  float ss = v * v;
#pragma unroll
  for (int m = 1; m < 64; m <<= 1) ss += __shfl_xor(ss, m, 64);
  float rr = rsqrtf(ss * (1.f / 64.f) + 1e-5f);
  float w = (half ? qn2 : qn1)[lane];
  int b = row >> 10, t = row & 1023;
  (half ? q2h : q1h)[(((size_t)(b * 16 + h)) * 1024 + t) * 64 + lane] =
      to_bf16(v * rr * w * 0.125f);
}

// ---------------- per-head RMSNorm of k1/k2 + v passthrough ----------------
__global__ __launch_bounds__(256) void k_rms_kv(const bf16_t* __restrict__ kv3,
                                                const float* __restrict__ kn1,
                                                const float* __restrict__ kn2,
                                                bf16_t* __restrict__ k1h,
                                                bf16_t* __restrict__ k2h,
                                                bf16_t* __restrict__ vh) {
  int wave = threadIdx.x >> 6, lane = threadIdx.x & 63;
  int g = blockIdx.x * 4 + wave;
  int row = g / 48, rem = g % 48;
  int part = rem >> 4, h = rem & 15;
  float v = bf2f(kv3[(size_t)row * 3072 + part * 1024 + h * 64 + lane]);
  int b = row >> 10, t = row & 1023;
  size_t oidx = (((size_t)(b * 16 + h)) * 1024 + t) * 64 + lane;
  if (part == 2) {
    vh[oidx] = to_bf16(v);
  } else {
    float ss = v * v;
#pragma unroll
    for (int m = 1; m < 64; m <<= 1) ss += __shfl_xor(ss, m, 64);
    float rr = rsqrtf(ss * (1.f / 64.f) + 1e-5f);
    float w = (part ? kn2 : kn1)[lane];
    (part ? k2h : k1h)[oidx] = to_bf16(v * rr * w);
  }
}

// ---------------- flash attention, S^T trick: P never touches LDS ----------------
// grid (16, 64); block 128 (2 waves x 32 q rows). Q pre-scaled by 1/8.
// vt is per-head transposed V: vt[bh][d][t].
// FUSE: yio[a] = yio[a] - softplus(lmb[h]) * attn_out  (second stream)
template <bool FUSE>
__global__ __launch_bounds__(128) void k_attn(const bf16_t* __restrict__ qh,
                                              const bf16_t* __restrict__ kh,
                                              const bf16_t* __restrict__ vt,
                                              const float* __restrict__ lmb,
                                              float* __restrict__ yio) {
  __shared__ bf16_t Ks[4096];  // [kv][d] XOR-swizzled 16B granules
  __shared__ bf16_t Vs[4096];  // [d][kv] XOR-swizzled 16B granules
  const int tid = threadIdx.x;
  const int wave = tid >> 6, lane = tid & 63;
  const int ln = lane & 15, lq = lane >> 4;
  const int swz = ln & 7;
  const int bh = blockIdx.y;
  const int qw = blockIdx.x * 64 + wave * 32;
  const bf16_t* qb = qh + (size_t)bh * 65536;
  const bf16_t* kb = kh + (size_t)bh * 65536;
  const bf16_t* vb = vt + (size_t)bh * 65536;

  // Q B-frags: lane holds Q[m=ln][d=ks*32+lq*8+j]
  bf16x8 qf[2][2];
#pragma unroll
  for (int mt = 0; mt < 2; mt++)
#pragma unroll
    for (int ks = 0; ks < 2; ks++)
      qf[mt][ks] = *(const bf16x8*)(qb + (size_t)(qw + mt * 16 + ln) * 64 + ks * 32 + lq * 8);

  f32x4 O[2][4];
  float lp[2] = {0.f, 0.f};
#pragma unroll
  for (int mt = 0; mt < 2; mt++)
#pragma unroll
    for (int nt = 0; nt < 4; nt++) O[mt][nt] = (f32x4){0.f, 0.f, 0.f, 0.f};

  for (int kv0 = 0; kv0 < TKV_; kv0 += 64) {
    __syncthreads();
#pragma unroll
    for (int rnd = 0; rnd < 4; rnd++) {
      int c = rnd * 128 + tid;
      int row = c >> 3;
      int blk = (c & 7) ^ (row & 7);
      int ldsoff = (rnd * 128 + wave * 64) * 16;
      gload_lds16(kb + (size_t)(kv0 + row) * 64 + blk * 8, (char*)Ks + ldsoff);
      gload_lds16(vb + (size_t)row * 1024 + kv0 + blk * 8, (char*)Vs + ldsoff);
    }
    asm volatile("s_waitcnt vmcnt(0)" ::: "memory");
    __syncthreads();

    // K A-frags: kf[ks][t] = K[t*16+ln][ks*32+lq*8 ..+7]
    bf16x8 kf[2][4];
#pragma unroll
    for (int ks = 0; ks < 2; ks++)
#pragma unroll
      for (int t = 0; t < 4; t++)
        kf[ks][t] = *(const bf16x8*)(Ks + ((t * 16 + ln) * 8 + ((4 * ks + lq) ^ swz)) * 8);

    // V B-frags for permuted-k PV: vf[u][nt], k=lq*8+j -> kv = u*32 + (j>=4)*16 + lq*4 + (j&3)
    bf16x8 vf[2][4];
#pragma unroll
    for (int u = 0; u < 2; u++)
#pragma unroll
      for (int nt = 0; nt < 4; nt++) {
        bf16x4 lo = *(const bf16x4*)(Vs + ((nt * 16 + ln) * 8 + ((u * 4 + (lq >> 1)) ^ swz)) * 8 +
                                     (lq & 1) * 4);
        bf16x4 hi = *(const bf16x4*)(Vs + ((nt * 16 + ln) * 8 + ((u * 4 + 2 + (lq >> 1)) ^ swz)) * 8 +
                                     (lq & 1) * 4);
        bf16x8 v;
#pragma unroll
        for (int j = 0; j < 4; j++) {
          v[j] = lo[j];
          v[4 + j] = hi[j];
        }
        vf[u][nt] = v;
      }

#pragma unroll
    for (int mt = 0; mt < 2; mt++) {
      // S^T tiles: s[t] holds S[m=ln][kv = t*16 + lq*4 + r]
      f32x4 s[4];
#pragma unroll
      for (int t = 0; t < 4; t++) s[t] = (f32x4){0.f, 0.f, 0.f, 0.f};
#pragma unroll
      for (int ks = 0; ks < 2; ks++)
#pragma unroll
        for (int t = 0; t < 4; t++)
          s[t] = __builtin_amdgcn_mfma_f32_16x16x32_bf16(kf[ks][t], qf[mt][ks], s[t], 0, 0, 0);
      // softmax numerator (scores bounded by 8: no max subtraction needed)
      bf16x8 pf[2];
      float l = 0.f;
#pragma unroll
      for (int t = 0; t < 4; t++)
#pragma unroll
        for (int r = 0; r < 4; r++) {
          float e = __expf(s[t][r]);
          l += e;
          pf[t >> 1][(t & 1) * 4 + r] = to_bf16(e);
        }
      lp[mt] += l;
      // PV: P already in A-frag layout
#pragma unroll
      for (int u = 0; u < 2; u++)
#pragma unroll
        for (int nt = 0; nt < 4; nt++)
          O[mt][nt] = __builtin_amdgcn_mfma_f32_16x16x32_bf16(pf[u], vf[u][nt], O[mt][nt], 0, 0, 0);
    }
  }

  float c = 0.f;
  if (FUSE) c = log1pf(__expf(lmb[bh & 15]));
#pragma unroll
  for (int mt = 0; mt < 2; mt++) {
    float l = lp[mt];
    l += __shfl_xor(l, 16, 64);
    l += __shfl_xor(l, 32, 64);  // full row-sum for row ln at every lane
    float linv[4];
#pragma unroll
    for (int r = 0; r < 4; r++) linv[r] = 1.f / __shfl(l, lq * 4 + r, 64);
#pragma unroll
    for (int nt = 0; nt < 4; nt++)
#pragma unroll
      for (int r = 0; r < 4; r++) {
        size_t a = ((size_t)bh * TQ_ + qw + mt * 16 + lq * 4 + r) * 64 + nt * 16 + ln;
        float val = O[mt][nt][r] * linv[r];
        if (FUSE)
          yio[a] = yio[a] - c * val;
        else
          yio[a] = val;
      }
  }
}

// ---------------- GroupNorm partial stats (4 blocks per bh) ----------------
__global__ __launch_bounds__(256) void k_gn_part(const float* __restrict__ y,
                                                 float* __restrict__ part) {
  int bh = blockIdx.x >> 2, qp = blockIdx.x & 3;
  const float4* p = (const float4*)(y + (size_t)bh * 65536 + qp * 16384);
  float s = 0.f, ss = 0.f;
  for (int i = threadIdx.x; i < 4096; i += 256) {
    float4 v = p[i];
    s += v.x + v.y + v.z + v.w;
    ss += v.x * v.x + v.y * v.y + v.z * v.z + v.w * v.w;
  }
#pragma unroll
  for (int m = 1; m < 64; m <<= 1) {
    s += __shfl_xor(s, m, 64);
    ss += __shfl_xor(ss, m, 64);
  }
  __shared__ float red[8];
  int wv = threadIdx.x >> 6;
  if ((threadIdx.x & 63) == 0) {
    red[wv] = s;
    red[4 + wv] = ss;
  }
  __syncthreads();
  if (threadIdx.x == 0) {
    part[blockIdx.x * 2] = red[0] + red[1] + red[2] + red[3];
    part[blockIdx.x * 2 + 1] = red[4] + red[5] + red[6] + red[7];
  }
}

__global__ __launch_bounds__(64) void k_gn_comb(const float* __restrict__ part,
                                                float* __restrict__ stats) {
  int bh = threadIdx.x;
  float S = 0.f, SS = 0.f;
#pragma unroll
  for (int p = 0; p < 4; p++) {
    S += part[(bh * 4 + p) * 2];
    SS += part[(bh * 4 + p) * 2 + 1];
  }
  float mean = S * (1.f / 65536.f);
  float var = SS * (1.f / 65536.f) - mean * mean;
  stats[bh * 2] = mean;
  stats[bh * 2 + 1] = rsqrtf(var + 1e-5f);
}

// ---------------- GroupNorm apply + transpose to (B,TQ,D) bf16 ----------------
__global__ __launch_bounds__(256) void k_gn_apply(const float* __restrict__ y,
                                                  const float* __restrict__ stats,
                                                  const float* __restrict__ gw,
                                                  const float* __restrict__ gb,
                                                  bf16_t* __restrict__ yn) {
  int idx = blockIdx.x * 256 + threadIdx.x;
  int i = idx * 4;
  int bh = i >> 16;
  int h = bh & 15, b = bh >> 4;
  float mean = stats[bh * 2], rstd = stats[bh * 2 + 1];
  float4 a = *(const float4*)(y + i);
  int rem = i & 65535;
  int t = rem >> 6, d = rem & 63;
  float4 gwv = *(const float4*)(gw + h * 64 + d);
  float4 gbv = *(const float4*)(gb + h * 64 + d);
  float o0 = (a.x - mean) * rstd * gwv.x + gbv.x;
  float o1 = (a.y - mean) * rstd * gwv.y + gbv.y;
  float o2 = (a.z - mean) * rstd * gwv.z + gbv.z;
  float o3 = (a.w - mean) * rstd * gwv.w + gbv.w;
  bf16x4 o = {to_bf16(o0), to_bf16(o1), to_bf16(o2), to_bf16(o3)};
  *(bf16x4*)(yn + ((size_t)(b * 1024 + t)) * 1024 + h * 64 + d) = o;
}

extern "C" void kernel_launch(void* const* d_in, const int* in_sizes, int n_in,
                              void* d_out, int out_size, void* d_ws, size_t ws_size,
                              hipStream_t stream) {
  const float* x_q = (const float*)d_in[0];
  const float* x_kv = (const float*)d_in[1];
  const float* Wq = (const float*)d_in[2];
  const float* Wkv = (const float*)d_in[3];
  const float* Wc = (const float*)d_in[4];
  const float* qn1 = (const float*)d_in[5];
  const float* kn1 = (const float*)d_in[6];
  const float* qn2 = (const float*)d_in[7];
  const float* kn2 = (const float*)d_in[8];
  const float* gn_w = (const float*)d_in[9];
  const float* gn_b = (const float*)d_in[10];
  const float* lmb = (const float*)d_in[11];

  const size_t MB = (size_t)1 << 20;
  char* ws = (char*)d_ws;
  bf16_t* xq_bf = (bf16_t*)(ws + 0 * MB);    // 8 MB (reused as vt later)
  bf16_t* xkv_bf = (bf16_t*)(ws + 8 * MB);   // 8 MB
  bf16_t* Wqt = (bf16_t*)(ws + 16 * MB);     // 4 MB
  bf16_t* Wkvt = (bf16_t*)(ws + 20 * MB);    // 6 MB
  bf16_t* Wct = (bf16_t*)(ws + 26 * MB);     // 2 MB
  bf16_t* q12 = (bf16_t*)(ws + 28 * MB);     // 16 MB
  bf16_t* kv3 = (bf16_t*)(ws + 44 * MB);     // 24 MB
  bf16_t* q1h = (bf16_t*)(ws + 68 * MB);     // 8 MB
  bf16_t* q2h = (bf16_t*)(ws + 76 * MB);
  bf16_t* k1h = (bf16_t*)(ws + 84 * MB);
  bf16_t* k2h = (bf16_t*)(ws + 92 * MB);
  bf16_t* vh = (bf16_t*)(ws + 100 * MB);
  float* y1 = (float*)(ws + 108 * MB);       // 16 MB fp32
  bf16_t* yn = (bf16_t*)(ws + 124 * MB);     // 8 MB
  float* stats = (float*)(ws + 132 * MB);    // 128 floats
  float* part = (float*)(ws + 132 * MB + 4096);  // 512 floats
  bf16_t* vt = (bf16_t*)(ws + 0 * MB);       // reuses xq_bf region (free after GEMMs)

  k_f2b<<<4096, 256, 0, stream>>>(x_q, xq_bf, 1048576);
  k_f2b<<<4096, 256, 0, stream>>>(x_kv, xkv_bf, 1048576);
  k_trb<<<dim3(64, 32), 256, 0, stream>>>(Wq, Wqt, 1024, 2048);
  k_trb<<<dim3(96, 32), 256, 0, stream>>>(Wkv, Wkvt, 1024, 3072);
  k_trb<<<dim3(32, 32), 256, 0, stream>>>(Wc, Wct, 1024, 1024);
  k_gemm<true><<<dim3(16, 32), 256, 0, stream>>>(xq_bf, Wqt, q12, 2048, 1024);
  k_gemm<true><<<dim3(24, 32), 256, 0, stream>>>(xkv_bf, Wkvt, kv3, 3072, 1024);
  k_rms_q<<<32768, 256, 0, stream>>>(q12, qn1, qn2, q1h, q2h);
  k_rms_kv<<<49152, 256, 0, stream>>>(kv3, kn1, kn2, k1h, k2h, vh);
  k_trv<<<dim3(16, 64), 256, 0, stream>>>(vh, vt);
  k_attn<false><<<dim3(16, 64), 128, 0, stream>>>(q1h, k1h, vt, lmb, y1);
  k_attn<true><<<dim3(16, 64), 128, 0, stream>>>(q2h, k2h, vt, lmb, y1);
  k_gn_part<<<256, 256, 0, stream>>>(y1, part);
  k_gn_comb<<<1, 64, 0, stream>>>(part, stats);
  k_gn_apply<<<4096, 256, 0, stream>>>(y1, stats, gn_w, gn_b, yn);
  k_gemm<false><<<dim3(8, 32), 256, 0, stream>>>(yn, Wct, d_out, 1024, 1024);
}

// Round 3
// 280.473 us; speedup vs baseline: 1.4718x; 1.2064x over previous
//
#include <hip/hip_runtime.h>
#include <cstdint>
#include <cstddef>

#define B_ 4
#define TQ_ 1024
#define TKV_ 1024
#define D_ 1024
#define H_ 16
#define HD_ 64

typedef __bf16 bf16_t;
typedef bf16_t bf16x4 __attribute__((ext_vector_type(4)));
typedef bf16_t bf16x8 __attribute__((ext_vector_type(8)));
typedef float f32x4 __attribute__((ext_vector_type(4)));

__device__ __forceinline__ bf16_t to_bf16(float f) {
  uint32_t u = __builtin_bit_cast(uint32_t, f);
  u += 0x7fffu + ((u >> 16) & 1u);
  uint16_t h = (uint16_t)(u >> 16);
  return __builtin_bit_cast(bf16_t, h);
}
__device__ __forceinline__ float bf2f(bf16_t b) {
  uint32_t u = ((uint32_t)__builtin_bit_cast(uint16_t, b)) << 16;
  return __builtin_bit_cast(float, u);
}
__device__ __forceinline__ void gload_lds16(const void* g, void* l) {
  __builtin_amdgcn_global_load_lds((const __attribute__((address_space(1))) void*)g,
                                   (__attribute__((address_space(3))) void*)l, 16, 0, 0);
}

// ---------------- fp32 -> bf16 for both activations, one launch ----------------
__global__ __launch_bounds__(256) void k_f2b2(const float* __restrict__ xq,
                                              const float* __restrict__ xkv,
                                              bf16_t* __restrict__ oq,
                                              bf16_t* __restrict__ okv) {
  int blk = blockIdx.x;
  const float* in = (blk < 4096) ? xq : xkv;
  bf16_t* out = (blk < 4096) ? oq : okv;
  int i = (blk & 4095) * 256 + threadIdx.x;
  float4 v = ((const float4*)in)[i];
  bf16x4 o = {to_bf16(v.x), to_bf16(v.y), to_bf16(v.z), to_bf16(v.w)};
  *(bf16x4*)(out + (size_t)i * 4) = o;
}

// ---------------- transpose+convert all three weights, one launch ----------------
// Wq (1024x2048) -> Wqt (2048x1024); Wkv (1024x3072) -> Wkvt; Wc (1024x1024) -> Wct
__global__ __launch_bounds__(256) void k_trb3(const float* __restrict__ Wq,
                                              const float* __restrict__ Wkv,
                                              const float* __restrict__ Wc,
                                              bf16_t* __restrict__ Wqt,
                                              bf16_t* __restrict__ Wkvt,
                                              bf16_t* __restrict__ Wct) {
  __shared__ float tile[32][33];
  int x = blockIdx.x;
  const float* in;
  bf16_t* out;
  int C, c0;
  if (x < 64) { in = Wq; out = Wqt; C = 2048; c0 = x * 32; }
  else if (x < 160) { in = Wkv; out = Wkvt; C = 3072; c0 = (x - 64) * 32; }
  else { in = Wc; out = Wct; C = 1024; c0 = (x - 160) * 32; }
  int r0 = blockIdx.y * 32;
  int tx = threadIdx.x & 31, ty = threadIdx.x >> 5;
#pragma unroll
  for (int i = 0; i < 4; i++)
    tile[ty + i * 8][tx] = in[(size_t)(r0 + ty + i * 8) * C + c0 + tx];
  __syncthreads();
#pragma unroll
  for (int i = 0; i < 4; i++) {
    int rr = ty + i * 8;
    out[(size_t)(c0 + rr) * 1024 + r0 + tx] = to_bf16(tile[tx][rr]);
  }
}

// ---------------- per-head V transpose straight out of kv3 ----------------
// kv3[row=b*1024+t][2048 + h*64 + d] -> vt[bh][d][t]
__global__ __launch_bounds__(256) void k_trv(const bf16_t* __restrict__ kv3,
                                             bf16_t* __restrict__ out) {
  __shared__ bf16_t tile[64][65];
  int bh = blockIdx.y;
  int b = bh >> 4, h = bh & 15;
  int t0 = blockIdx.x * 64;
  const bf16_t* ib = kv3 + (size_t)(b * 1024 + t0) * 3072 + 2048 + h * 64;
  bf16_t* ob = out + (size_t)bh * 65536;
  int r = threadIdx.x >> 2, c8 = (threadIdx.x & 3) * 16;
  bf16x8 a = *(const bf16x8*)(ib + (size_t)r * 3072 + c8);
  bf16x8 bb = *(const bf16x8*)(ib + (size_t)r * 3072 + c8 + 8);
#pragma unroll
  for (int j = 0; j < 8; j++) {
    tile[c8 + j][r] = a[j];
    tile[c8 + 8 + j][r] = bb[j];
  }
  __syncthreads();
  int d = threadIdx.x >> 2, tt = (threadIdx.x & 3) * 16;
  bf16x8 o0, o1;
#pragma unroll
  for (int j = 0; j < 8; j++) {
    o0[j] = tile[d][tt + j];
    o1[j] = tile[d][tt + 8 + j];
  }
  *(bf16x8*)(ob + (size_t)d * 1024 + t0 + tt) = o0;
  *(bf16x8*)(ob + (size_t)d * 1024 + t0 + tt + 8) = o1;
}

// ---------------- bf16 GEMM 128x128: C[M,N] = A[M,K] * Bt[N,K]^T ----------------
__global__ __launch_bounds__(256, 2) void k_gemm(const bf16_t* __restrict__ A,
                                                 const bf16_t* __restrict__ Bt,
                                                 bf16_t* __restrict__ C, int N, int K) {
  __shared__ bf16_t As[128 * 32];
  __shared__ bf16_t Bs[128 * 32];
  const int tid = threadIdx.x;
  const int wave = tid >> 6, lane = tid & 63;
  const int ln = lane & 15, lq = lane >> 4;
  const int m0 = blockIdx.y * 128, n0 = blockIdx.x * 128;
  const int wm = (wave >> 1) * 64, wn = (wave & 1) * 64;
  f32x4 acc[4][4];
#pragma unroll
  for (int i = 0; i < 4; i++)
#pragma unroll
    for (int j = 0; j < 4; j++) acc[i][j] = (f32x4){0.f, 0.f, 0.f, 0.f};

  for (int k0 = 0; k0 < K; k0 += 32) {
#pragma unroll
    for (int rnd = 0; rnd < 2; rnd++) {
      int c = rnd * 256 + tid;
      int row = c >> 2, col = (c & 3) * 8;
      int ldsoff = (rnd * 256 + wave * 64) * 16;
      gload_lds16(A + (size_t)(m0 + row) * K + k0 + col, (char*)As + ldsoff);
      gload_lds16(Bt + (size_t)(n0 + row) * K + k0 + col, (char*)Bs + ldsoff);
    }
    asm volatile("s_waitcnt vmcnt(0)" ::: "memory");
    __syncthreads();
    bf16x8 af[4], bfr[4];
#pragma unroll
    for (int i = 0; i < 4; i++) {
      af[i] = *(const bf16x8*)(As + (wm + i * 16 + ln) * 32 + lq * 8);
      bfr[i] = *(const bf16x8*)(Bs + (wn + i * 16 + ln) * 32 + lq * 8);
    }
#pragma unroll
    for (int i = 0; i < 4; i++)
#pragma unroll
      for (int j = 0; j < 4; j++)
        acc[i][j] = __builtin_amdgcn_mfma_f32_16x16x32_bf16(af[i], bfr[j], acc[i][j], 0, 0, 0);
    __syncthreads();
  }
#pragma unroll
  for (int i = 0; i < 4; i++)
#pragma unroll
    for (int j = 0; j < 4; j++)
#pragma unroll
      for (int r = 0; r < 4; r++) {
        int row = m0 + wm + i * 16 + lq * 4 + r;
        int col = n0 + wn + j * 16 + ln;
        C[(size_t)row * N + col] = to_bf16(acc[i][j][r]);
      }
}

// ---------------- bf16 GEMM 128x64 tile (fp32 out) for the N=1024 output proj ----------------
__global__ __launch_bounds__(256, 2) void k_gemm64(const bf16_t* __restrict__ A,
                                                   const bf16_t* __restrict__ Bt,
                                                   float* __restrict__ C, int N, int K) {
  __shared__ bf16_t As[128 * 32];
  __shared__ bf16_t Bs[64 * 32];
  const int tid = threadIdx.x;
  const int wave = tid >> 6, lane = tid & 63;
  const int ln = lane & 15, lq = lane >> 4;
  const int m0 = blockIdx.y * 128, n0 = blockIdx.x * 64;
  const int wm = wave * 32;
  f32x4 acc[2][4];
#pragma unroll
  for (int i = 0; i < 2; i++)
#pragma unroll
    for (int j = 0; j < 4; j++) acc[i][j] = (f32x4){0.f, 0.f, 0.f, 0.f};

  for (int k0 = 0; k0 < K; k0 += 32) {
#pragma unroll
    for (int rnd = 0; rnd < 2; rnd++) {
      int c = rnd * 256 + tid;
      int row = c >> 2, col = (c & 3) * 8;
      int ldsoff = (rnd * 256 + wave * 64) * 16;
      gload_lds16(A + (size_t)(m0 + row) * K + k0 + col, (char*)As + ldsoff);
    }
    {
      int row = tid >> 2, col = (tid & 3) * 8;
      int ldsoff = (wave * 64) * 16;
      gload_lds16(Bt + (size_t)(n0 + row) * K + k0 + col, (char*)Bs + ldsoff);
    }
    asm volatile("s_waitcnt vmcnt(0)" ::: "memory");
    __syncthreads();
    bf16x8 af[2], bfr[4];
#pragma unroll
    for (int i = 0; i < 2; i++)
      af[i] = *(const bf16x8*)(As + (wm + i * 16 + ln) * 32 + lq * 8);
#pragma unroll
    for (int j = 0; j < 4; j++)
      bfr[j] = *(const bf16x8*)(Bs + (j * 16 + ln) * 32 + lq * 8);
#pragma unroll
    for (int i = 0; i < 2; i++)
#pragma unroll
      for (int j = 0; j < 4; j++)
        acc[i][j] = __builtin_amdgcn_mfma_f32_16x16x32_bf16(af[i], bfr[j], acc[i][j], 0, 0, 0);
    __syncthreads();
  }
#pragma unroll
  for (int i = 0; i < 2; i++)
#pragma unroll
    for (int j = 0; j < 4; j++)
#pragma unroll
      for (int r = 0; r < 4; r++) {
        int row = m0 + wm + i * 16 + lq * 4 + r;
        int col = n0 + j * 16 + ln;
        C[(size_t)row * N + col] = acc[i][j][r];
      }
}

// ---------------- per-head RMSNorm of k1/k2 ----------------
__global__ __launch_bounds__(256) void k_rms_k(const bf16_t* __restrict__ kv3,
                                               const float* __restrict__ kn1,
                                               const float* __restrict__ kn2,
                                               bf16_t* __restrict__ k1h,
                                               bf16_t* __restrict__ k2h) {
  int wave = threadIdx.x >> 6, lane = threadIdx.x & 63;
  int g = blockIdx.x * 4 + wave;   // [0, 4096*32)
  int row = g >> 5, rem = g & 31;
  int part = rem >> 4, h = rem & 15;
  float v = bf2f(kv3[(size_t)row * 3072 + part * 1024 + h * 64 + lane]);
  float ss = v * v;
#pragma unroll
  for (int m = 1; m < 64; m <<= 1) ss += __shfl_xor(ss, m, 64);
  float rr = rsqrtf(ss * (1.f / 64.f) + 1e-5f);
  float w = (part ? kn2 : kn1)[lane];
  int b = row >> 10, t = row & 1023;
  size_t oidx = (((size_t)(b * 16 + h)) * 1024 + t) * 64 + lane;
  (part ? k2h : k1h)[oidx] = to_bf16(v * rr * w);
}

// ---------------- fused dual-stream flash attention ----------------
// grid (64=bh, 8=qblock) -> all q-blocks of a bh on one XCD (id%8 = bh%8).
// block 256 = 4 waves x 32 q-rows. Q read from q12 with RMS+qn+0.125 fused.
// Output y[bh][t][d] = attn1 - softplus(lmb)*attn2, bf16.
__global__ __launch_bounds__(256, 2) void k_attn2(const bf16_t* __restrict__ q12,
                                                  const bf16_t* __restrict__ k1h,
                                                  const bf16_t* __restrict__ k2h,
                                                  const bf16_t* __restrict__ vt,
                                                  const float* __restrict__ qn1,
                                                  const float* __restrict__ qn2,
                                                  const float* __restrict__ lmb,
                                                  bf16_t* __restrict__ y) {
  __shared__ bf16_t Ks[2][4096];  // [kv][d] XOR-swizzled 16B granules
  __shared__ bf16_t Vs[4096];     // [d][kv] XOR-swizzled 16B granules
  const int tid = threadIdx.x;
  const int wave = tid >> 6, lane = tid & 63;
  const int ln = lane & 15, lq = lane >> 4;
  const int swz = ln & 7;
  const int bh = blockIdx.x;
  const int b = bh >> 4, h = bh & 15;
  const int qw = blockIdx.y * 128 + wave * 32;
  const bf16_t* kb[2] = {k1h + (size_t)bh * 65536, k2h + (size_t)bh * 65536};
  const bf16_t* vb = vt + (size_t)bh * 65536;

  // ---- Q load (both streams) + fused RMSNorm * qn * 0.125 ----
  bf16x8 qf[2][2][2];  // [stream][mt][ks]
#pragma unroll
  for (int st = 0; st < 2; st++)
#pragma unroll
    for (int mt = 0; mt < 2; mt++)
#pragma unroll
      for (int ks = 0; ks < 2; ks++)
        qf[st][mt][ks] = *(const bf16x8*)(q12 + (size_t)(b * 1024 + qw + mt * 16 + ln) * 2048 +
                                          st * 1024 + h * 64 + ks * 32 + lq * 8);
#pragma unroll
  for (int st = 0; st < 2; st++) {
    const float* qn = st ? qn2 : qn1;
    float4 w0 = *(const float4*)(qn + lq * 8);
    float4 w1 = *(const float4*)(qn + lq * 8 + 4);
    float4 w2 = *(const float4*)(qn + 32 + lq * 8);
    float4 w3 = *(const float4*)(qn + 32 + lq * 8 + 4);
    float wv[2][8] = {{w0.x, w0.y, w0.z, w0.w, w1.x, w1.y, w1.z, w1.w},
                      {w2.x, w2.y, w2.z, w2.w, w3.x, w3.y, w3.z, w3.w}};
#pragma unroll
    for (int mt = 0; mt < 2; mt++) {
      float ssq = 0.f;
#pragma unroll
      for (int ks = 0; ks < 2; ks++)
#pragma unroll
        for (int j = 0; j < 8; j++) {
          float v = bf2f(qf[st][mt][ks][j]);
          ssq += v * v;
        }
      ssq += __shfl_xor(ssq, 16, 64);
      ssq += __shfl_xor(ssq, 32, 64);
      float rr = rsqrtf(ssq * (1.f / 64.f) + 1e-5f) * 0.125f;
#pragma unroll
      for (int ks = 0; ks < 2; ks++)
#pragma unroll
        for (int j = 0; j < 8; j++)
          qf[st][mt][ks][j] = to_bf16(bf2f(qf[st][mt][ks][j]) * rr * wv[ks][j]);
    }
  }

  f32x4 O[2][2][4];  // [stream][mt][nt]
  float lp[2][2] = {{0.f, 0.f}, {0.f, 0.f}};
#pragma unroll
  for (int st = 0; st < 2; st++)
#pragma unroll
    for (int mt = 0; mt < 2; mt++)
#pragma unroll
      for (int nt = 0; nt < 4; nt++) O[st][mt][nt] = (f32x4){0.f, 0.f, 0.f, 0.f};

  for (int kv0 = 0; kv0 < TKV_; kv0 += 64) {
    __syncthreads();
    // stage K1, K2 (8 KB each) and V (8 KB): 6 rounds x 4 KB
#pragma unroll
    for (int r = 0; r < 6; r++) {
      int a = r >> 1, r2 = r & 1;
      int g = r2 * 256 + tid;
      int row = g >> 3;
      int blk = (g & 7) ^ (row & 7);
      const bf16_t* src = (a < 2) ? (kb[a] + (size_t)(kv0 + row) * 64 + blk * 8)
                                  : (vb + (size_t)row * 1024 + kv0 + blk * 8);
      char* dst = (a < 2) ? ((char*)Ks + a * 8192) : (char*)Vs;
      gload_lds16(src, dst + (r2 * 256 + wave * 64) * 16);
    }
    asm volatile("s_waitcnt vmcnt(0)" ::: "memory");
    __syncthreads();

    // V B-frags: vf[u][nt], k=lq*8+j -> kv = u*32 + (j>=4)*16 + lq*4 + (j&3)
    bf16x8 vf[2][4];
#pragma unroll
    for (int u = 0; u < 2; u++)
#pragma unroll
      for (int nt = 0; nt < 4; nt++) {
        bf16x4 lo = *(const bf16x4*)(Vs + ((nt * 16 + ln) * 8 + ((u * 4 + (lq >> 1)) ^ swz)) * 8 +
                                     (lq & 1) * 4);
        bf16x4 hi = *(const bf16x4*)(Vs + ((nt * 16 + ln) * 8 + ((u * 4 + 2 + (lq >> 1)) ^ swz)) * 8 +
                                     (lq & 1) * 4);
        bf16x8 v;
#pragma unroll
        for (int j = 0; j < 4; j++) {
          v[j] = lo[j];
          v[4 + j] = hi[j];
        }
        vf[u][nt] = v;
      }

#pragma unroll
    for (int st = 0; st < 2; st++) {
      // K A-frags for this stream
      bf16x8 kf[2][4];
#pragma unroll
      for (int ks = 0; ks < 2; ks++)
#pragma unroll
        for (int t = 0; t < 4; t++)
          kf[ks][t] = *(const bf16x8*)(&Ks[st][((t * 16 + ln) * 8 + ((4 * ks + lq) ^ swz)) * 8]);
#pragma unroll
      for (int mt = 0; mt < 2; mt++) {
        f32x4 s[4];
#pragma unroll
        for (int t = 0; t < 4; t++) s[t] = (f32x4){0.f, 0.f, 0.f, 0.f};
#pragma unroll
        for (int ks = 0; ks < 2; ks++)
#pragma unroll
          for (int t = 0; t < 4; t++)
            s[t] = __builtin_amdgcn_mfma_f32_16x16x32_bf16(kf[ks][t], qf[st][mt][ks], s[t], 0, 0, 0);
        bf16x8 pf[2];
        float l = 0.f;
#pragma unroll
        for (int t = 0; t < 4; t++)
#pragma unroll
          for (int r = 0; r < 4; r++) {
            float e = __expf(s[t][r]);
            l += e;
            pf[t >> 1][(t & 1) * 4 + r] = to_bf16(e);
          }
        lp[st][mt] += l;
#pragma unroll
        for (int u = 0; u < 2; u++)
#pragma unroll
          for (int nt = 0; nt < 4; nt++)
            O[st][mt][nt] =
                __builtin_amdgcn_mfma_f32_16x16x32_bf16(pf[u], vf[u][nt], O[st][mt][nt], 0, 0, 0);
      }
    }
  }

  float c = log1pf(__expf(lmb[h]));
#pragma unroll
  for (int mt = 0; mt < 2; mt++) {
    float linv[2][4];
#pragma unroll
    for (int st = 0; st < 2; st++) {
      float l = lp[st][mt];
      l += __shfl_xor(l, 16, 64);
      l += __shfl_xor(l, 32, 64);  // row-sum for row ln at every lane
#pragma unroll
      for (int r = 0; r < 4; r++) linv[st][r] = 1.f / __shfl(l, lq * 4 + r, 64);
    }
#pragma unroll
    for (int nt = 0; nt < 4; nt++)
#pragma unroll
      for (int r = 0; r < 4; r++) {
        size_t a = ((size_t)bh * TQ_ + qw + mt * 16 + lq * 4 + r) * 64 + nt * 16 + ln;
        y[a] = to_bf16(O[0][mt][nt][r] * linv[0][r] - c * O[1][mt][nt][r] * linv[1][r]);
      }
  }
}

// ---------------- GroupNorm partial stats (4 blocks per bh), bf16 input ----------------
__global__ __launch_bounds__(256) void k_gn_part(const bf16_t* __restrict__ y,
                                                 float* __restrict__ part) {
  int bh = blockIdx.x >> 2, qp = blockIdx.x & 3;
  const bf16_t* p = y + (size_t)bh * 65536 + qp * 16384;
  float s = 0.f, ss = 0.f;
  for (int i = threadIdx.x; i < 2048; i += 256) {
    bf16x8 v = *(const bf16x8*)(p + i * 8);
#pragma unroll
    for (int j = 0; j < 8; j++) {
      float f = bf2f(v[j]);
      s += f;
      ss += f * f;
    }
  }
#pragma unroll
  for (int m = 1; m < 64; m <<= 1) {
    s += __shfl_xor(s, m, 64);
    ss += __shfl_xor(ss, m, 64);
  }
  __shared__ float red[8];
  int wv = threadIdx.x >> 6;
  if ((threadIdx.x & 63) == 0) {
    red[wv] = s;
    red[4 + wv] = ss;
  }
  __syncthreads();
  if (threadIdx.x == 0) {
    part[blockIdx.x * 2] = red[0] + red[1] + red[2] + red[3];
    part[blockIdx.x * 2 + 1] = red[4] + red[5] + red[6] + red[7];
  }
}

__global__ __launch_bounds__(64) void k_gn_comb(const float* __restrict__ part,
                                                float* __restrict__ stats) {
  int bh = threadIdx.x;
  float S = 0.f, SS = 0.f;
#pragma unroll
  for (int p = 0; p < 4; p++) {
    S += part[(bh * 4 + p) * 2];
    SS += part[(bh * 4 + p) * 2 + 1];
  }
  float mean = S * (1.f / 65536.f);
  float var = SS * (1.f / 65536.f) - mean * mean;
  stats[bh * 2] = mean;
  stats[bh * 2 + 1] = rsqrtf(var + 1e-5f);
}

// ---------------- GroupNorm apply + layout to (B,TQ,D) bf16 ----------------
__global__ __launch_bounds__(256) void k_gn_apply(const bf16_t* __restrict__ y,
                                                  const float* __restrict__ stats,
                                                  const float* __restrict__ gw,
                                                  const float* __restrict__ gb,
                                                  bf16_t* __restrict__ yn) {
  int idx = blockIdx.x * 256 + threadIdx.x;  // 8-elem granule over 4M elems
  int i = idx * 8;
  int bh = i >> 16;
  int h = bh & 15, b = bh >> 4;
  float mean = stats[bh * 2], rstd = stats[bh * 2 + 1];
  bf16x8 a = *(const bf16x8*)(y + i);
  int rem = i & 65535;
  int t = rem >> 6, d = rem & 63;
  bf16x8 o;
#pragma unroll
  for (int j = 0; j < 8; j++) {
    float f = (bf2f(a[j]) - mean) * rstd * gw[h * 64 + d + j] + gb[h * 64 + d + j];
    o[j] = to_bf16(f);
  }
  *(bf16x8*)(yn + ((size_t)(b * 1024 + t)) * 1024 + h * 64 + d) = o;
}

extern "C" void kernel_launch(void* const* d_in, const int* in_sizes, int n_in,
                              void* d_out, int out_size, void* d_ws, size_t ws_size,
                              hipStream_t stream) {
  const float* x_q = (const float*)d_in[0];
  const float* x_kv = (const float*)d_in[1];
  const float* Wq = (const float*)d_in[2];
  const float* Wkv = (const float*)d_in[3];
  const float* Wc = (const float*)d_in[4];
  const float* qn1 = (const float*)d_in[5];
  const float* kn1 = (const float*)d_in[6];
  const float* qn2 = (const float*)d_in[7];
  const float* kn2 = (const float*)d_in[8];
  const float* gn_w = (const float*)d_in[9];
  const float* gn_b = (const float*)d_in[10];
  const float* lmb = (const float*)d_in[11];

  const size_t MB = (size_t)1 << 20;
  char* ws = (char*)d_ws;
  bf16_t* xq_bf = (bf16_t*)(ws + 0 * MB);
  bf16_t* xkv_bf = (bf16_t*)(ws + 8 * MB);
  bf16_t* Wqt = (bf16_t*)(ws + 16 * MB);
  bf16_t* Wkvt = (bf16_t*)(ws + 20 * MB);
  bf16_t* Wct = (bf16_t*)(ws + 26 * MB);
  bf16_t* q12 = (bf16_t*)(ws + 28 * MB);
  bf16_t* kv3 = (bf16_t*)(ws + 44 * MB);
  bf16_t* k1h = (bf16_t*)(ws + 68 * MB);
  bf16_t* k2h = (bf16_t*)(ws + 76 * MB);
  bf16_t* vt = (bf16_t*)(ws + 84 * MB);
  bf16_t* y = (bf16_t*)(ws + 92 * MB);
  bf16_t* yn = (bf16_t*)(ws + 100 * MB);
  float* stats = (float*)(ws + 108 * MB);
  float* part = (float*)(ws + 108 * MB + 4096);

  k_f2b2<<<8192, 256, 0, stream>>>(x_q, x_kv, xq_bf, xkv_bf);
  k_trb3<<<dim3(192, 32), 256, 0, stream>>>(Wq, Wkv, Wc, Wqt, Wkvt, Wct);
  k_gemm<<<dim3(16, 32), 256, 0, stream>>>(xq_bf, Wqt, q12, 2048, 1024);
  k_gemm<<<dim3(24, 32), 256, 0, stream>>>(xkv_bf, Wkvt, kv3, 3072, 1024);
  k_rms_k<<<32768, 256, 0, stream>>>(kv3, kn1, kn2, k1h, k2h);
  k_trv<<<dim3(16, 64), 256, 0, stream>>>(kv3, vt);
  k_attn2<<<dim3(64, 8), 256, 0, stream>>>(q12, k1h, k2h, vt, qn1, qn2, lmb, y);
  k_gn_part<<<256, 256, 0, stream>>>(y, part);
  k_gn_comb<<<1, 64, 0, stream>>>(part, stats);
  k_gn_apply<<<2048, 256, 0, stream>>>(y, stats, gn_w, gn_b, yn);
  k_gemm64<<<dim3(16, 32), 256, 0, stream>>>(yn, Wct, (float*)d_out, 1024, 1024);
}

// Round 4
// 270.541 us; speedup vs baseline: 1.5259x; 1.0367x over previous
//
#include <hip/hip_runtime.h>
#include <cstdint>
#include <cstddef>

#define B_ 4
#define TQ_ 1024
#define TKV_ 1024
#define D_ 1024
#define H_ 16
#define HD_ 64

typedef __bf16 bf16_t;
typedef bf16_t bf16x4 __attribute__((ext_vector_type(4)));
typedef bf16_t bf16x8 __attribute__((ext_vector_type(8)));
typedef float f32x4 __attribute__((ext_vector_type(4)));

#if __has_builtin(__builtin_amdgcn_exp2f)
#define EXP2F __builtin_amdgcn_exp2f
#else
#define EXP2F exp2f
#endif

__device__ __forceinline__ bf16_t to_bf16(float f) {
  uint32_t u = __builtin_bit_cast(uint32_t, f);
  u += 0x7fffu + ((u >> 16) & 1u);
  uint16_t h = (uint16_t)(u >> 16);
  return __builtin_bit_cast(bf16_t, h);
}
__device__ __forceinline__ float bf2f(bf16_t b) {
  uint32_t u = ((uint32_t)__builtin_bit_cast(uint16_t, b)) << 16;
  return __builtin_bit_cast(float, u);
}
// pack two fp32 -> two bf16 (truncation) in ONE v_perm_b32
__device__ __forceinline__ uint32_t pack_bf16_trunc(float lo, float hi) {
  return __builtin_amdgcn_perm(__builtin_bit_cast(uint32_t, hi),
                               __builtin_bit_cast(uint32_t, lo), 0x07060302u);
}
__device__ __forceinline__ void gload_lds16(const void* g, void* l) {
  __builtin_amdgcn_global_load_lds((const __attribute__((address_space(1))) void*)g,
                                   (__attribute__((address_space(3))) void*)l, 16, 0, 0);
}

// ---------------- fp32 -> bf16 for both activations, one launch ----------------
__global__ __launch_bounds__(256) void k_f2b2(const float* __restrict__ xq,
                                              const float* __restrict__ xkv,
                                              bf16_t* __restrict__ oq,
                                              bf16_t* __restrict__ okv) {
  int blk = blockIdx.x;
  const float* in = (blk < 4096) ? xq : xkv;
  bf16_t* out = (blk < 4096) ? oq : okv;
  int i = (blk & 4095) * 256 + threadIdx.x;
  float4 v = ((const float4*)in)[i];
  bf16x4 o = {to_bf16(v.x), to_bf16(v.y), to_bf16(v.z), to_bf16(v.w)};
  *(bf16x4*)(out + (size_t)i * 4) = o;
}

// ---------------- transpose+convert all three weights, one launch ----------------
__global__ __launch_bounds__(256) void k_trb3(const float* __restrict__ Wq,
                                              const float* __restrict__ Wkv,
                                              const float* __restrict__ Wc,
                                              bf16_t* __restrict__ Wqt,
                                              bf16_t* __restrict__ Wkvt,
                                              bf16_t* __restrict__ Wct) {
  __shared__ float tile[32][33];
  int x = blockIdx.x;
  const float* in;
  bf16_t* out;
  int C, c0;
  if (x < 64) { in = Wq; out = Wqt; C = 2048; c0 = x * 32; }
  else if (x < 160) { in = Wkv; out = Wkvt; C = 3072; c0 = (x - 64) * 32; }
  else { in = Wc; out = Wct; C = 1024; c0 = (x - 160) * 32; }
  int r0 = blockIdx.y * 32;
  int tx = threadIdx.x & 31, ty = threadIdx.x >> 5;
#pragma unroll
  for (int i = 0; i < 4; i++)
    tile[ty + i * 8][tx] = in[(size_t)(r0 + ty + i * 8) * C + c0 + tx];
  __syncthreads();
#pragma unroll
  for (int i = 0; i < 4; i++) {
    int rr = ty + i * 8;
    out[(size_t)(c0 + rr) * 1024 + r0 + tx] = to_bf16(tile[tx][rr]);
  }
}

// ---------------- per-head V transpose: vh[bh][t][d] -> vt[bh][d][t] ----------------
__global__ __launch_bounds__(256) void k_trv(const bf16_t* __restrict__ in,
                                             bf16_t* __restrict__ out) {
  __shared__ bf16_t tile[64][65];
  int bh = blockIdx.y;
  int t0 = blockIdx.x * 64;
  const bf16_t* ib = in + (size_t)bh * 65536;
  bf16_t* ob = out + (size_t)bh * 65536;
  int r = threadIdx.x >> 2, c8 = (threadIdx.x & 3) * 16;
  bf16x8 a = *(const bf16x8*)(ib + (size_t)(t0 + r) * 64 + c8);
  bf16x8 bb = *(const bf16x8*)(ib + (size_t)(t0 + r) * 64 + c8 + 8);
#pragma unroll
  for (int j = 0; j < 8; j++) {
    tile[c8 + j][r] = a[j];
    tile[c8 + 8 + j][r] = bb[j];
  }
  __syncthreads();
  int d = threadIdx.x >> 2, tt = (threadIdx.x & 3) * 16;
  bf16x8 o0, o1;
#pragma unroll
  for (int j = 0; j < 8; j++) {
    o0[j] = tile[d][tt + j];
    o1[j] = tile[d][tt + 8 + j];
  }
  *(bf16x8*)(ob + (size_t)d * 1024 + t0 + tt) = o0;
  *(bf16x8*)(ob + (size_t)d * 1024 + t0 + tt + 8) = o1;
}

// ---------------- merged Q+KV projection GEMM, K-RMSNorm fused into KV epilogue ----
// grid (40, 32): x<16 -> q12 = xq@Wq ; x>=16 -> kv = xkv@Wkv with per-head RMS on
// k1/k2 parts (direct head-layout writes) and head-layout write of v.
__global__ __launch_bounds__(256, 2) void k_gemm_qkv(const bf16_t* __restrict__ xq,
                                                     const bf16_t* __restrict__ xkv,
                                                     const bf16_t* __restrict__ Wqt,
                                                     const bf16_t* __restrict__ Wkvt,
                                                     const float* __restrict__ kn1,
                                                     const float* __restrict__ kn2,
                                                     bf16_t* __restrict__ q12,
                                                     bf16_t* __restrict__ k1h,
                                                     bf16_t* __restrict__ k2h,
                                                     bf16_t* __restrict__ vh) {
  __shared__ bf16_t As[128 * 32];
  __shared__ bf16_t Bs[128 * 32];
  const int tid = threadIdx.x;
  const int wave = tid >> 6, lane = tid & 63;
  const int ln = lane & 15, lq = lane >> 4;
  const bool isq = blockIdx.x < 16;
  const bf16_t* A = isq ? xq : xkv;
  const bf16_t* Bt = isq ? Wqt : Wkvt;
  const int n0 = (isq ? blockIdx.x : blockIdx.x - 16) * 128;
  const int m0 = blockIdx.y * 128;
  const int wm = (wave >> 1) * 64, wn = (wave & 1) * 64;
  f32x4 acc[4][4];
#pragma unroll
  for (int i = 0; i < 4; i++)
#pragma unroll
    for (int j = 0; j < 4; j++) acc[i][j] = (f32x4){0.f, 0.f, 0.f, 0.f};

  for (int k0 = 0; k0 < 1024; k0 += 32) {
#pragma unroll
    for (int rnd = 0; rnd < 2; rnd++) {
      int c = rnd * 256 + tid;
      int row = c >> 2, col = (c & 3) * 8;
      int ldsoff = (rnd * 256 + wave * 64) * 16;
      gload_lds16(A + (size_t)(m0 + row) * 1024 + k0 + col, (char*)As + ldsoff);
      gload_lds16(Bt + (size_t)(n0 + row) * 1024 + k0 + col, (char*)Bs + ldsoff);
    }
    asm volatile("s_waitcnt vmcnt(0)" ::: "memory");
    __syncthreads();
    bf16x8 af[4], bfr[4];
#pragma unroll
    for (int i = 0; i < 4; i++) {
      af[i] = *(const bf16x8*)(As + (wm + i * 16 + ln) * 32 + lq * 8);
      bfr[i] = *(const bf16x8*)(Bs + (wn + i * 16 + ln) * 32 + lq * 8);
    }
#pragma unroll
    for (int i = 0; i < 4; i++)
#pragma unroll
      for (int j = 0; j < 4; j++)
        acc[i][j] = __builtin_amdgcn_mfma_f32_16x16x32_bf16(af[i], bfr[j], acc[i][j], 0, 0, 0);
    __syncthreads();
  }

  if (isq) {
#pragma unroll
    for (int i = 0; i < 4; i++)
#pragma unroll
      for (int j = 0; j < 4; j++)
#pragma unroll
        for (int r = 0; r < 4; r++) {
          int row = m0 + wm + i * 16 + lq * 4 + r;
          int col = n0 + wn + j * 16 + ln;
          q12[(size_t)row * 2048 + col] = to_bf16(acc[i][j][r]);
        }
  } else {
    const int col0 = n0 + wn;        // multiple of 64 -> whole head per wave-half
    const int part = col0 >> 10;     // 0:k1, 1:k2, 2:v
    const int h = (col0 >> 6) & 15;
    if (part < 2) {
      const float* kn = part ? kn2 : kn1;
      bf16_t* dst = part ? k2h : k1h;
      float kw[4];
#pragma unroll
      for (int j = 0; j < 4; j++) kw[j] = kn[j * 16 + ln];
#pragma unroll
      for (int i = 0; i < 4; i++)
#pragma unroll
        for (int r = 0; r < 4; r++) {
          float ss = 0.f;
#pragma unroll
          for (int j = 0; j < 4; j++) ss += acc[i][j][r] * acc[i][j][r];
          ss += __shfl_xor(ss, 1, 64);
          ss += __shfl_xor(ss, 2, 64);
          ss += __shfl_xor(ss, 4, 64);
          ss += __shfl_xor(ss, 8, 64);
          float rstd = rsqrtf(ss * (1.f / 64.f) + 1e-5f);
          int m = m0 + wm + i * 16 + lq * 4 + r;
          int b = m >> 10, t = m & 1023;
          size_t base = (((size_t)(b * 16 + h)) * 1024 + t) * 64;
#pragma unroll
          for (int j = 0; j < 4; j++)
            dst[base + j * 16 + ln] = to_bf16(acc[i][j][r] * rstd * kw[j]);
        }
    } else {
#pragma unroll
      for (int i = 0; i < 4; i++)
#pragma unroll
        for (int r = 0; r < 4; r++) {
          int m = m0 + wm + i * 16 + lq * 4 + r;
          int b = m >> 10, t = m & 1023;
          size_t base = (((size_t)(b * 16 + h)) * 1024 + t) * 64;
#pragma unroll
          for (int j = 0; j < 4; j++)
            vh[base + j * 16 + ln] = to_bf16(acc[i][j][r]);
        }
    }
  }
}

// ---------------- bf16 GEMM 128x64 tile (fp32 out) for the output projection ----------------
__global__ __launch_bounds__(256, 2) void k_gemm64(const bf16_t* __restrict__ A,
                                                   const bf16_t* __restrict__ Bt,
                                                   float* __restrict__ C, int N, int K) {
  __shared__ bf16_t As[128 * 32];
  __shared__ bf16_t Bs[64 * 32];
  const int tid = threadIdx.x;
  const int wave = tid >> 6, lane = tid & 63;
  const int ln = lane & 15, lq = lane >> 4;
  const int m0 = blockIdx.y * 128, n0 = blockIdx.x * 64;
  const int wm = wave * 32;
  f32x4 acc[2][4];
#pragma unroll
  for (int i = 0; i < 2; i++)
#pragma unroll
    for (int j = 0; j < 4; j++) acc[i][j] = (f32x4){0.f, 0.f, 0.f, 0.f};

  for (int k0 = 0; k0 < K; k0 += 32) {
#pragma unroll
    for (int rnd = 0; rnd < 2; rnd++) {
      int c = rnd * 256 + tid;
      int row = c >> 2, col = (c & 3) * 8;
      int ldsoff = (rnd * 256 + wave * 64) * 16;
      gload_lds16(A + (size_t)(m0 + row) * K + k0 + col, (char*)As + ldsoff);
    }
    {
      int row = tid >> 2, col = (tid & 3) * 8;
      int ldsoff = (wave * 64) * 16;
      gload_lds16(Bt + (size_t)(n0 + row) * K + k0 + col, (char*)Bs + ldsoff);
    }
    asm volatile("s_waitcnt vmcnt(0)" ::: "memory");
    __syncthreads();
    bf16x8 af[2], bfr[4];
#pragma unroll
    for (int i = 0; i < 2; i++)
      af[i] = *(const bf16x8*)(As + (wm + i * 16 + ln) * 32 + lq * 8);
#pragma unroll
    for (int j = 0; j < 4; j++)
      bfr[j] = *(const bf16x8*)(Bs + (j * 16 + ln) * 32 + lq * 8);
#pragma unroll
    for (int i = 0; i < 2; i++)
#pragma unroll
      for (int j = 0; j < 4; j++)
        acc[i][j] = __builtin_amdgcn_mfma_f32_16x16x32_bf16(af[i], bfr[j], acc[i][j], 0, 0, 0);
    __syncthreads();
  }
#pragma unroll
  for (int i = 0; i < 2; i++)
#pragma unroll
    for (int j = 0; j < 4; j++)
#pragma unroll
      for (int r = 0; r < 4; r++) {
        int row = m0 + wm + i * 16 + lq * 4 + r;
        int col = n0 + j * 16 + ln;
        C[(size_t)row * N + col] = acc[i][j][r];
      }
}

// ---------------- fused dual-stream flash attention ----------------
// grid (64=bh, 16=qblock); block 256 = 4 waves x 16 q-rows (64 q/block).
// XCD: linear id % 8 = bh % 8 -> all q-blocks of a bh share one XCD's L2.
// Q RMS fused on load; scale 0.125*log2e folded -> exp2 in softmax.
// P packed to bf16 by truncation (v_perm). y = attn1 - softplus(lmb)*attn2.
__global__ __launch_bounds__(256, 4) void k_attn2(const bf16_t* __restrict__ q12,
                                                  const bf16_t* __restrict__ k1h,
                                                  const bf16_t* __restrict__ k2h,
                                                  const bf16_t* __restrict__ vt,
                                                  const float* __restrict__ qn1,
                                                  const float* __restrict__ qn2,
                                                  const float* __restrict__ lmb,
                                                  bf16_t* __restrict__ y) {
  __shared__ bf16_t Ks[2][4096];  // [kv][d] XOR-swizzled 16B granules
  __shared__ bf16_t Vs[4096];     // [d][kv] XOR-swizzled 16B granules
  const int tid = threadIdx.x;
  const int wave = tid >> 6, lane = tid & 63;
  const int ln = lane & 15, lq = lane >> 4;
  const int swz = ln & 7;
  const int bh = blockIdx.x;
  const int b = bh >> 4, h = bh & 15;
  const int q0 = blockIdx.y * 64 + wave * 16;
  const bf16_t* kb[2] = {k1h + (size_t)bh * 65536, k2h + (size_t)bh * 65536};
  const bf16_t* vb = vt + (size_t)bh * 65536;

  // ---- Q load (both streams) + fused RMSNorm * qn * (0.125*log2e) ----
  bf16x8 qf[2][2];  // [stream][ks]
#pragma unroll
  for (int st = 0; st < 2; st++)
#pragma unroll
    for (int ks = 0; ks < 2; ks++)
      qf[st][ks] = *(const bf16x8*)(q12 + (size_t)(b * 1024 + q0 + ln) * 2048 + st * 1024 +
                                    h * 64 + ks * 32 + lq * 8);
#pragma unroll
  for (int st = 0; st < 2; st++) {
    const float* qn = st ? qn2 : qn1;
    float ssq = 0.f;
#pragma unroll
    for (int ks = 0; ks < 2; ks++)
#pragma unroll
      for (int j = 0; j < 8; j++) {
        float v = bf2f(qf[st][ks][j]);
        ssq += v * v;
      }
    ssq += __shfl_xor(ssq, 16, 64);
    ssq += __shfl_xor(ssq, 32, 64);
    float rr = rsqrtf(ssq * (1.f / 64.f) + 1e-5f) * (0.125f * 1.44269504f);
#pragma unroll
    for (int ks = 0; ks < 2; ks++)
#pragma unroll
      for (int j = 0; j < 8; j++)
        qf[st][ks][j] = to_bf16(bf2f(qf[st][ks][j]) * rr * qn[ks * 32 + lq * 8 + j]);
  }

  f32x4 O[2][4];  // [stream][nt]
  float lp[2] = {0.f, 0.f};
#pragma unroll
  for (int st = 0; st < 2; st++)
#pragma unroll
    for (int nt = 0; nt < 4; nt++) O[st][nt] = (f32x4){0.f, 0.f, 0.f, 0.f};

  for (int kv0 = 0; kv0 < TKV_; kv0 += 64) {
    __syncthreads();
    // stage K1, K2 (8 KB each) and V (8 KB): 6 rounds x 4 KB
#pragma unroll
    for (int r = 0; r < 6; r++) {
      int a = r >> 1, r2 = r & 1;
      int g = r2 * 256 + tid;
      int row = g >> 3;
      int blk = (g & 7) ^ (row & 7);
      const bf16_t* src = (a < 2) ? (kb[a] + (size_t)(kv0 + row) * 64 + blk * 8)
                                  : (vb + (size_t)row * 1024 + kv0 + blk * 8);
      char* dst = (a < 2) ? ((char*)Ks + a * 8192) : (char*)Vs;
      gload_lds16(src, dst + (r2 * 256 + wave * 64) * 16);
    }
    asm volatile("s_waitcnt vmcnt(0)" ::: "memory");
    __syncthreads();

#pragma unroll
    for (int st = 0; st < 2; st++) {
      // K A-frags
      bf16x8 kf[2][4];
#pragma unroll
      for (int ks = 0; ks < 2; ks++)
#pragma unroll
        for (int t = 0; t < 4; t++)
          kf[ks][t] = *(const bf16x8*)(&Ks[st][((t * 16 + ln) * 8 + ((4 * ks + lq) ^ swz)) * 8]);
      // S^T tiles: s[t] = S[m=ln][kv = t*16 + lq*4 + r]
      f32x4 s[4];
#pragma unroll
      for (int t = 0; t < 4; t++) s[t] = (f32x4){0.f, 0.f, 0.f, 0.f};
#pragma unroll
      for (int ks = 0; ks < 2; ks++)
#pragma unroll
        for (int t = 0; t < 4; t++)
          s[t] = __builtin_amdgcn_mfma_f32_16x16x32_bf16(kf[ks][t], qf[st][ks], s[t], 0, 0, 0);
      // softmax numerator: exp2 (log2e pre-folded), truncating bf16 pack
      uint32_t pfu[2][4];
      float l = 0.f;
#pragma unroll
      for (int t = 0; t < 4; t++) {
        float e0 = EXP2F(s[t][0]), e1 = EXP2F(s[t][1]);
        float e2 = EXP2F(s[t][2]), e3 = EXP2F(s[t][3]);
        l += (e0 + e1) + (e2 + e3);
        pfu[t >> 1][(t & 1) * 2] = pack_bf16_trunc(e0, e1);
        pfu[t >> 1][(t & 1) * 2 + 1] = pack_bf16_trunc(e2, e3);
      }
      lp[st] += l;
      // PV: P already in A-frag layout; V B-frags streamed from LDS
#pragma unroll
      for (int u = 0; u < 2; u++) {
        bf16x8 pf = __builtin_bit_cast(bf16x8, *(uint4*)pfu[u]);
#pragma unroll
        for (int nt = 0; nt < 4; nt++) {
          uint2 lo = *(const uint2*)(Vs + ((nt * 16 + ln) * 8 + ((u * 4 + (lq >> 1)) ^ swz)) * 8 +
                                     (lq & 1) * 4);
          uint2 hi = *(const uint2*)(Vs + ((nt * 16 + ln) * 8 + ((u * 4 + 2 + (lq >> 1)) ^ swz)) * 8 +
                                     (lq & 1) * 4);
          uint4 vq = {lo.x, lo.y, hi.x, hi.y};
          bf16x8 vfrag = __builtin_bit_cast(bf16x8, vq);
          O[st][nt] = __builtin_amdgcn_mfma_f32_16x16x32_bf16(pf, vfrag, O[st][nt], 0, 0, 0);
        }
      }
    }
  }

  float c = log1pf(__expf(lmb[h]));
  float linv[2][4];
#pragma unroll
  for (int st = 0; st < 2; st++) {
    float l = lp[st];
    l += __shfl_xor(l, 16, 64);
    l += __shfl_xor(l, 32, 64);  // row-sum for row ln at every lane
#pragma unroll
    for (int r = 0; r < 4; r++) linv[st][r] = 1.f / __shfl(l, lq * 4 + r, 64);
  }
#pragma unroll
  for (int nt = 0; nt < 4; nt++)
#pragma unroll
    for (int r = 0; r < 4; r++) {
      size_t a = ((size_t)bh * TQ_ + q0 + lq * 4 + r) * 64 + nt * 16 + ln;
      y[a] = to_bf16(O[0][nt][r] * linv[0][r] - c * O[1][nt][r] * linv[1][r]);
    }
}

// ---------------- GroupNorm partial stats (4 blocks per bh), bf16 input ----------------
__global__ __launch_bounds__(256) void k_gn_part(const bf16_t* __restrict__ y,
                                                 float* __restrict__ part) {
  int bh = blockIdx.x >> 2, qp = blockIdx.x & 3;
  const bf16_t* p = y + (size_t)bh * 65536 + qp * 16384;
  float s = 0.f, ss = 0.f;
  for (int i = threadIdx.x; i < 2048; i += 256) {
    bf16x8 v = *(const bf16x8*)(p + i * 8);
#pragma unroll
    for (int j = 0; j < 8; j++) {
      float f = bf2f(v[j]);
      s += f;
      ss += f * f;
    }
  }
#pragma unroll
  for (int m = 1; m < 64; m <<= 1) {
    s += __shfl_xor(s, m, 64);
    ss += __shfl_xor(ss, m, 64);
  }
  __shared__ float red[8];
  int wv = threadIdx.x >> 6;
  if ((threadIdx.x & 63) == 0) {
    red[wv] = s;
    red[4 + wv] = ss;
  }
  __syncthreads();
  if (threadIdx.x == 0) {
    part[blockIdx.x * 2] = red[0] + red[1] + red[2] + red[3];
    part[blockIdx.x * 2 + 1] = red[4] + red[5] + red[6] + red[7];
  }
}

__global__ __launch_bounds__(64) void k_gn_comb(const float* __restrict__ part,
                                                float* __restrict__ stats) {
  int bh = threadIdx.x;
  float S = 0.f, SS = 0.f;
#pragma unroll
  for (int p = 0; p < 4; p++) {
    S += part[(bh * 4 + p) * 2];
    SS += part[(bh * 4 + p) * 2 + 1];
  }
  float mean = S * (1.f / 65536.f);
  float var = SS * (1.f / 65536.f) - mean * mean;
  stats[bh * 2] = mean;
  stats[bh * 2 + 1] = rsqrtf(var + 1e-5f);
}

// ---------------- GroupNorm apply + layout to (B,TQ,D) bf16 ----------------
__global__ __launch_bounds__(256) void k_gn_apply(const bf16_t* __restrict__ y,
                                                  const float* __restrict__ stats,
                                                  const float* __restrict__ gw,
                                                  const float* __restrict__ gb,
                                                  bf16_t* __restrict__ yn) {
  int idx = blockIdx.x * 256 + threadIdx.x;
  int i = idx * 8;
  int bh = i >> 16;
  int h = bh & 15, b = bh >> 4;
  float mean = stats[bh * 2], rstd = stats[bh * 2 + 1];
  bf16x8 a = *(const bf16x8*)(y + i);
  int rem = i & 65535;
  int t = rem >> 6, d = rem & 63;
  bf16x8 o;
#pragma unroll
  for (int j = 0; j < 8; j++) {
    float f = (bf2f(a[j]) - mean) * rstd * gw[h * 64 + d + j] + gb[h * 64 + d + j];
    o[j] = to_bf16(f);
  }
  *(bf16x8*)(yn + ((size_t)(b * 1024 + t)) * 1024 + h * 64 + d) = o;
}

extern "C" void kernel_launch(void* const* d_in, const int* in_sizes, int n_in,
                              void* d_out, int out_size, void* d_ws, size_t ws_size,
                              hipStream_t stream) {
  const float* x_q = (const float*)d_in[0];
  const float* x_kv = (const float*)d_in[1];
  const float* Wq = (const float*)d_in[2];
  const float* Wkv = (const float*)d_in[3];
  const float* Wc = (const float*)d_in[4];
  const float* qn1 = (const float*)d_in[5];
  const float* kn1 = (const float*)d_in[6];
  const float* qn2 = (const float*)d_in[7];
  const float* kn2 = (const float*)d_in[8];
  const float* gn_w = (const float*)d_in[9];
  const float* gn_b = (const float*)d_in[10];
  const float* lmb = (const float*)d_in[11];

  const size_t MB = (size_t)1 << 20;
  char* ws = (char*)d_ws;
  bf16_t* xq_bf = (bf16_t*)(ws + 0 * MB);
  bf16_t* xkv_bf = (bf16_t*)(ws + 8 * MB);
  bf16_t* Wqt = (bf16_t*)(ws + 16 * MB);
  bf16_t* Wkvt = (bf16_t*)(ws + 20 * MB);
  bf16_t* Wct = (bf16_t*)(ws + 26 * MB);
  bf16_t* q12 = (bf16_t*)(ws + 28 * MB);
  bf16_t* k1h = (bf16_t*)(ws + 44 * MB);
  bf16_t* k2h = (bf16_t*)(ws + 52 * MB);
  bf16_t* vh = (bf16_t*)(ws + 60 * MB);
  bf16_t* vt = (bf16_t*)(ws + 68 * MB);
  bf16_t* y = (bf16_t*)(ws + 76 * MB);
  bf16_t* yn = (bf16_t*)(ws + 84 * MB);
  float* stats = (float*)(ws + 92 * MB);
  float* part = (float*)(ws + 92 * MB + 4096);

  k_f2b2<<<8192, 256, 0, stream>>>(x_q, x_kv, xq_bf, xkv_bf);
  k_trb3<<<dim3(192, 32), 256, 0, stream>>>(Wq, Wkv, Wc, Wqt, Wkvt, Wct);
  k_gemm_qkv<<<dim3(40, 32), 256, 0, stream>>>(xq_bf, xkv_bf, Wqt, Wkvt, kn1, kn2,
                                               q12, k1h, k2h, vh);
  k_trv<<<dim3(16, 64), 256, 0, stream>>>(vh, vt);
  k_attn2<<<dim3(64, 16), 256, 0, stream>>>(q12, k1h, k2h, vt, qn1, qn2, lmb, y);
  k_gn_part<<<256, 256, 0, stream>>>(y, part);
  k_gn_comb<<<1, 64, 0, stream>>>(part, stats);
  k_gn_apply<<<2048, 256, 0, stream>>>(y, stats, gn_w, gn_b, yn);
  k_gemm64<<<dim3(16, 32), 256, 0, stream>>>(yn, Wct, (float*)d_out, 1024, 1024);
}

// Round 5
// 268.617 us; speedup vs baseline: 1.5368x; 1.0072x over previous
//
#include <hip/hip_runtime.h>
#include <cstdint>
#include <cstddef>

#define B_ 4
#define TQ_ 1024
#define TKV_ 1024
#define D_ 1024
#define H_ 16
#define HD_ 64

typedef __bf16 bf16_t;
typedef bf16_t bf16x4 __attribute__((ext_vector_type(4)));
typedef bf16_t bf16x8 __attribute__((ext_vector_type(8)));
typedef float f32x4 __attribute__((ext_vector_type(4)));

#if __has_builtin(__builtin_amdgcn_exp2f)
#define EXP2F __builtin_amdgcn_exp2f
#else
#define EXP2F exp2f
#endif

__device__ __forceinline__ bf16_t to_bf16(float f) {
  uint32_t u = __builtin_bit_cast(uint32_t, f);
  u += 0x7fffu + ((u >> 16) & 1u);
  uint16_t h = (uint16_t)(u >> 16);
  return __builtin_bit_cast(bf16_t, h);
}
__device__ __forceinline__ float bf2f(bf16_t b) {
  uint32_t u = ((uint32_t)__builtin_bit_cast(uint16_t, b)) << 16;
  return __builtin_bit_cast(float, u);
}
// pack two fp32 -> two bf16 (truncation) in ONE v_perm_b32
__device__ __forceinline__ uint32_t pack_bf16_trunc(float lo, float hi) {
  return __builtin_amdgcn_perm(__builtin_bit_cast(uint32_t, hi),
                               __builtin_bit_cast(uint32_t, lo), 0x07060302u);
}
__device__ __forceinline__ void gload_lds16(const void* g, void* l) {
  __builtin_amdgcn_global_load_lds((const __attribute__((address_space(1))) void*)g,
                                   (__attribute__((address_space(3))) void*)l, 16, 0, 0);
}

// ---------------- prep: f2b of activations + weight transpose + zero(part) ----------------
// blocks [0,8192): fp32->bf16 activations; [8192,14336): weight transpose+convert.
__global__ __launch_bounds__(256) void k_prep(const float* __restrict__ xq,
                                              const float* __restrict__ xkv,
                                              const float* __restrict__ Wq,
                                              const float* __restrict__ Wkv,
                                              const float* __restrict__ Wc,
                                              bf16_t* __restrict__ oq,
                                              bf16_t* __restrict__ okv,
                                              bf16_t* __restrict__ Wqt,
                                              bf16_t* __restrict__ Wkvt,
                                              bf16_t* __restrict__ Wct,
                                              float* __restrict__ part) {
  int blk = blockIdx.x;
  if (blk == 0 && threadIdx.x < 128) part[threadIdx.x] = 0.f;
  if (blk < 8192) {
    const float* in = (blk < 4096) ? xq : xkv;
    bf16_t* out = (blk < 4096) ? oq : okv;
    int i = (blk & 4095) * 256 + threadIdx.x;
    float4 v = ((const float4*)in)[i];
    bf16x4 o = {to_bf16(v.x), to_bf16(v.y), to_bf16(v.z), to_bf16(v.w)};
    *(bf16x4*)(out + (size_t)i * 4) = o;
  } else {
    __shared__ float tile[32][33];
    int t = blk - 8192;           // 0..6143
    int x = t % 192, yb = t / 192;  // yb 0..31
    const float* in;
    bf16_t* out;
    int C, c0;
    if (x < 64) { in = Wq; out = Wqt; C = 2048; c0 = x * 32; }
    else if (x < 160) { in = Wkv; out = Wkvt; C = 3072; c0 = (x - 64) * 32; }
    else { in = Wc; out = Wct; C = 1024; c0 = (x - 160) * 32; }
    int r0 = yb * 32;
    int tx = threadIdx.x & 31, ty = threadIdx.x >> 5;
#pragma unroll
    for (int i = 0; i < 4; i++)
      tile[ty + i * 8][tx] = in[(size_t)(r0 + ty + i * 8) * C + c0 + tx];
    __syncthreads();
#pragma unroll
    for (int i = 0; i < 4; i++) {
      int rr = ty + i * 8;
      out[(size_t)(c0 + rr) * 1024 + r0 + tx] = to_bf16(tile[tx][rr]);
    }
  }
}

// ---------------- merged Q+KV projection GEMM, XCD-supertiled ----------------
// flat grid 1280; xcd = fid&7. Each XCD: q-region (4 n-bands x 16 m-bands) then
// kv-region (6 n-bands x same 16 m-bands) -> per-XCD L2 working set ~5 MB.
// K-RMSNorm fused into k1/k2 epilogue; V written TRANSPOSED (vt[bh][d][t]).
__global__ __launch_bounds__(256, 2) void k_gemm_qkv(const bf16_t* __restrict__ xq,
                                                     const bf16_t* __restrict__ xkv,
                                                     const bf16_t* __restrict__ Wqt,
                                                     const bf16_t* __restrict__ Wkvt,
                                                     const float* __restrict__ kn1,
                                                     const float* __restrict__ kn2,
                                                     bf16_t* __restrict__ q12,
                                                     bf16_t* __restrict__ k1h,
                                                     bf16_t* __restrict__ k2h,
                                                     bf16_t* __restrict__ vt) {
  __shared__ bf16_t As[128 * 32];
  __shared__ bf16_t Bs[128 * 32];
  const int tid = threadIdx.x;
  const int wave = tid >> 6, lane = tid & 63;
  const int ln = lane & 15, lq = lane >> 4;

  const int fid = blockIdx.x;
  const int xcd = fid & 7, l = fid >> 3;  // l in [0,160)
  bool isq;
  int xb, yb;
  if (l < 64) {  // q: 4 x-bands x 16 y-bands per XCD
    isq = true;
    xb = (xcd & 3) * 4 + (l & 3);
    yb = (xcd >> 2) * 16 + (l >> 2);
  } else {  // kv: 6 x-bands x 16 y-bands per XCD
    isq = false;
    int l2 = l - 64;
    xb = (xcd & 3) * 6 + l2 % 6;
    yb = (xcd >> 2) * 16 + l2 / 6;
  }
  const bf16_t* A = isq ? xq : xkv;
  const bf16_t* Bt = isq ? Wqt : Wkvt;
  const int n0 = xb * 128, m0 = yb * 128;
  const int wm = (wave >> 1) * 64, wn = (wave & 1) * 64;
  f32x4 acc[4][4];
#pragma unroll
  for (int i = 0; i < 4; i++)
#pragma unroll
    for (int j = 0; j < 4; j++) acc[i][j] = (f32x4){0.f, 0.f, 0.f, 0.f};

  for (int k0 = 0; k0 < 1024; k0 += 32) {
#pragma unroll
    for (int rnd = 0; rnd < 2; rnd++) {
      int c = rnd * 256 + tid;
      int row = c >> 2, col = (c & 3) * 8;
      int ldsoff = (rnd * 256 + wave * 64) * 16;
      gload_lds16(A + (size_t)(m0 + row) * 1024 + k0 + col, (char*)As + ldsoff);
      gload_lds16(Bt + (size_t)(n0 + row) * 1024 + k0 + col, (char*)Bs + ldsoff);
    }
    asm volatile("s_waitcnt vmcnt(0)" ::: "memory");
    __syncthreads();
    bf16x8 af[4], bfr[4];
#pragma unroll
    for (int i = 0; i < 4; i++) {
      af[i] = *(const bf16x8*)(As + (wm + i * 16 + ln) * 32 + lq * 8);
      bfr[i] = *(const bf16x8*)(Bs + (wn + i * 16 + ln) * 32 + lq * 8);
    }
#pragma unroll
    for (int i = 0; i < 4; i++)
#pragma unroll
      for (int j = 0; j < 4; j++)
        acc[i][j] = __builtin_amdgcn_mfma_f32_16x16x32_bf16(af[i], bfr[j], acc[i][j], 0, 0, 0);
    __syncthreads();
  }

  if (isq) {
#pragma unroll
    for (int i = 0; i < 4; i++)
#pragma unroll
      for (int j = 0; j < 4; j++)
#pragma unroll
        for (int r = 0; r < 4; r++) {
          int row = m0 + wm + i * 16 + lq * 4 + r;
          int col = n0 + wn + j * 16 + ln;
          q12[(size_t)row * 2048 + col] = to_bf16(acc[i][j][r]);
        }
  } else {
    const int col0 = n0 + wn;        // multiple of 64 -> whole head per wave-half
    const int part3 = col0 >> 10;    // 0:k1, 1:k2, 2:v
    const int h = (col0 >> 6) & 15;
    const int b = m0 >> 10;
    const int bh = b * 16 + h;
    if (part3 < 2) {
      const float* kn = part3 ? kn2 : kn1;
      bf16_t* dst = part3 ? k2h : k1h;
      float kw[4];
#pragma unroll
      for (int j = 0; j < 4; j++) kw[j] = kn[j * 16 + ln];
#pragma unroll
      for (int i = 0; i < 4; i++)
#pragma unroll
        for (int r = 0; r < 4; r++) {
          float ss = 0.f;
#pragma unroll
          for (int j = 0; j < 4; j++) ss += acc[i][j][r] * acc[i][j][r];
          ss += __shfl_xor(ss, 1, 64);
          ss += __shfl_xor(ss, 2, 64);
          ss += __shfl_xor(ss, 4, 64);
          ss += __shfl_xor(ss, 8, 64);
          float rstd = rsqrtf(ss * (1.f / 64.f) + 1e-5f);
          int m = m0 + wm + i * 16 + lq * 4 + r;
          int t = m & 1023;
          size_t base = ((size_t)bh * 1024 + t) * 64;
#pragma unroll
          for (int j = 0; j < 4; j++)
            dst[base + j * 16 + ln] = to_bf16(acc[i][j][r] * rstd * kw[j]);
        }
    } else {
      // V: write transposed vt[bh][d][t], packed 4 x bf16 along t
      bf16_t* obase = vt + (size_t)bh * 65536;
#pragma unroll
      for (int i = 0; i < 4; i++) {
        int t0 = (m0 & 1023) + wm + i * 16 + lq * 4;
#pragma unroll
        for (int j = 0; j < 4; j++) {
          bf16x4 pv;
#pragma unroll
          for (int r = 0; r < 4; r++) pv[r] = to_bf16(acc[i][j][r]);
          *(bf16x4*)(obase + (size_t)(j * 16 + ln) * 1024 + t0) = pv;
        }
      }
    }
  }
}

// ---------------- bf16 GEMM 128x64 tile (fp32 out), XCD-supertiled ----------------
__global__ __launch_bounds__(256, 2) void k_gemm64(const bf16_t* __restrict__ A,
                                                   const bf16_t* __restrict__ Bt,
                                                   float* __restrict__ C, int N, int K) {
  __shared__ bf16_t As[128 * 32];
  __shared__ bf16_t Bs[64 * 32];
  const int tid = threadIdx.x;
  const int wave = tid >> 6, lane = tid & 63;
  const int ln = lane & 15, lq = lane >> 4;
  const int fid = blockIdx.x;  // flat 512
  const int xcd = fid & 7, l = fid >> 3;  // 0..63
  const int lx = l & 1, ly = (l >> 1) & 15, yh = l >> 5;
  const int n0 = (xcd * 2 + lx) * 64;
  const int m0 = (yh * 16 + ly) * 128;
  const int wm = wave * 32;
  f32x4 acc[2][4];
#pragma unroll
  for (int i = 0; i < 2; i++)
#pragma unroll
    for (int j = 0; j < 4; j++) acc[i][j] = (f32x4){0.f, 0.f, 0.f, 0.f};

  for (int k0 = 0; k0 < K; k0 += 32) {
#pragma unroll
    for (int rnd = 0; rnd < 2; rnd++) {
      int c = rnd * 256 + tid;
      int row = c >> 2, col = (c & 3) * 8;
      int ldsoff = (rnd * 256 + wave * 64) * 16;
      gload_lds16(A + (size_t)(m0 + row) * K + k0 + col, (char*)As + ldsoff);
    }
    {
      int row = tid >> 2, col = (tid & 3) * 8;
      int ldsoff = (wave * 64) * 16;
      gload_lds16(Bt + (size_t)(n0 + row) * K + k0 + col, (char*)Bs + ldsoff);
    }
    asm volatile("s_waitcnt vmcnt(0)" ::: "memory");
    __syncthreads();
    bf16x8 af[2], bfr[4];
#pragma unroll
    for (int i = 0; i < 2; i++)
      af[i] = *(const bf16x8*)(As + (wm + i * 16 + ln) * 32 + lq * 8);
#pragma unroll
    for (int j = 0; j < 4; j++)
      bfr[j] = *(const bf16x8*)(Bs + (j * 16 + ln) * 32 + lq * 8);
#pragma unroll
    for (int i = 0; i < 2; i++)
#pragma unroll
      for (int j = 0; j < 4; j++)
        acc[i][j] = __builtin_amdgcn_mfma_f32_16x16x32_bf16(af[i], bfr[j], acc[i][j], 0, 0, 0);
    __syncthreads();
  }
#pragma unroll
  for (int i = 0; i < 2; i++)
#pragma unroll
    for (int j = 0; j < 4; j++)
#pragma unroll
      for (int r = 0; r < 4; r++) {
        int row = m0 + wm + i * 16 + lq * 4 + r;
        int col = n0 + j * 16 + ln;
        C[(size_t)row * N + col] = acc[i][j][r];
      }
}

// ---------------- fused dual-stream flash attention + GN partial stats ----------------
// grid (64=bh, 16=qblock); block 256 = 4 waves x 16 q-rows.
// XCD: linear id % 8 = bh % 8 -> all q-blocks of a bh share one XCD's L2.
__global__ __launch_bounds__(256, 4) void k_attn2(const bf16_t* __restrict__ q12,
                                                  const bf16_t* __restrict__ k1h,
                                                  const bf16_t* __restrict__ k2h,
                                                  const bf16_t* __restrict__ vt,
                                                  const float* __restrict__ qn1,
                                                  const float* __restrict__ qn2,
                                                  const float* __restrict__ lmb,
                                                  bf16_t* __restrict__ y,
                                                  float* __restrict__ part) {
  __shared__ bf16_t Ks[2][4096];  // [kv][d] XOR-swizzled 16B granules
  __shared__ bf16_t Vs[4096];     // [d][kv] XOR-swizzled 16B granules
  const int tid = threadIdx.x;
  const int wave = tid >> 6, lane = tid & 63;
  const int ln = lane & 15, lq = lane >> 4;
  const int swz = ln & 7;
  const int bh = blockIdx.x;
  const int b = bh >> 4, h = bh & 15;
  const int q0 = blockIdx.y * 64 + wave * 16;
  const bf16_t* kb[2] = {k1h + (size_t)bh * 65536, k2h + (size_t)bh * 65536};
  const bf16_t* vb = vt + (size_t)bh * 65536;

  // ---- Q load (both streams) + fused RMSNorm * qn * (0.125*log2e) ----
  bf16x8 qf[2][2];  // [stream][ks]
#pragma unroll
  for (int st = 0; st < 2; st++)
#pragma unroll
    for (int ks = 0; ks < 2; ks++)
      qf[st][ks] = *(const bf16x8*)(q12 + (size_t)(b * 1024 + q0 + ln) * 2048 + st * 1024 +
                                    h * 64 + ks * 32 + lq * 8);
#pragma unroll
  for (int st = 0; st < 2; st++) {
    const float* qn = st ? qn2 : qn1;
    float ssq = 0.f;
#pragma unroll
    for (int ks = 0; ks < 2; ks++)
#pragma unroll
      for (int j = 0; j < 8; j++) {
        float v = bf2f(qf[st][ks][j]);
        ssq += v * v;
      }
    ssq += __shfl_xor(ssq, 16, 64);
    ssq += __shfl_xor(ssq, 32, 64);
    float rr = rsqrtf(ssq * (1.f / 64.f) + 1e-5f) * (0.125f * 1.44269504f);
#pragma unroll
    for (int ks = 0; ks < 2; ks++)
#pragma unroll
      for (int j = 0; j < 8; j++)
        qf[st][ks][j] = to_bf16(bf2f(qf[st][ks][j]) * rr * qn[ks * 32 + lq * 8 + j]);
  }

  f32x4 O[2][4];  // [stream][nt]
  float lp[2] = {0.f, 0.f};
#pragma unroll
  for (int st = 0; st < 2; st++)
#pragma unroll
    for (int nt = 0; nt < 4; nt++) O[st][nt] = (f32x4){0.f, 0.f, 0.f, 0.f};

  for (int kv0 = 0; kv0 < TKV_; kv0 += 64) {
    __syncthreads();
#pragma unroll
    for (int r = 0; r < 6; r++) {
      int a = r >> 1, r2 = r & 1;
      int g = r2 * 256 + tid;
      int row = g >> 3;
      int blk = (g & 7) ^ (row & 7);
      const bf16_t* src = (a < 2) ? (kb[a] + (size_t)(kv0 + row) * 64 + blk * 8)
                                  : (vb + (size_t)row * 1024 + kv0 + blk * 8);
      char* dst = (a < 2) ? ((char*)Ks + a * 8192) : (char*)Vs;
      gload_lds16(src, dst + (r2 * 256 + wave * 64) * 16);
    }
    asm volatile("s_waitcnt vmcnt(0)" ::: "memory");
    __syncthreads();

#pragma unroll
    for (int st = 0; st < 2; st++) {
      bf16x8 kf[2][4];
#pragma unroll
      for (int ks = 0; ks < 2; ks++)
#pragma unroll
        for (int t = 0; t < 4; t++)
          kf[ks][t] = *(const bf16x8*)(&Ks[st][((t * 16 + ln) * 8 + ((4 * ks + lq) ^ swz)) * 8]);
      f32x4 s[4];
#pragma unroll
      for (int t = 0; t < 4; t++) s[t] = (f32x4){0.f, 0.f, 0.f, 0.f};
#pragma unroll
      for (int ks = 0; ks < 2; ks++)
#pragma unroll
        for (int t = 0; t < 4; t++)
          s[t] = __builtin_amdgcn_mfma_f32_16x16x32_bf16(kf[ks][t], qf[st][ks], s[t], 0, 0, 0);
      uint32_t pfu[2][4];
      float l = 0.f;
#pragma unroll
      for (int t = 0; t < 4; t++) {
        float e0 = EXP2F(s[t][0]), e1 = EXP2F(s[t][1]);
        float e2 = EXP2F(s[t][2]), e3 = EXP2F(s[t][3]);
        l += (e0 + e1) + (e2 + e3);
        pfu[t >> 1][(t & 1) * 2] = pack_bf16_trunc(e0, e1);
        pfu[t >> 1][(t & 1) * 2 + 1] = pack_bf16_trunc(e2, e3);
      }
      lp[st] += l;
#pragma unroll
      for (int u = 0; u < 2; u++) {
        bf16x8 pf = __builtin_bit_cast(bf16x8, *(uint4*)pfu[u]);
#pragma unroll
        for (int nt = 0; nt < 4; nt++) {
          uint2 lo = *(const uint2*)(Vs + ((nt * 16 + ln) * 8 + ((u * 4 + (lq >> 1)) ^ swz)) * 8 +
                                     (lq & 1) * 4);
          uint2 hi = *(const uint2*)(Vs + ((nt * 16 + ln) * 8 + ((u * 4 + 2 + (lq >> 1)) ^ swz)) * 8 +
                                     (lq & 1) * 4);
          uint4 vq = {lo.x, lo.y, hi.x, hi.y};
          bf16x8 vfrag = __builtin_bit_cast(bf16x8, vq);
          O[st][nt] = __builtin_amdgcn_mfma_f32_16x16x32_bf16(pf, vfrag, O[st][nt], 0, 0, 0);
        }
      }
    }
  }

  float c = log1pf(__expf(lmb[h]));
  float linv[2][4];
#pragma unroll
  for (int st = 0; st < 2; st++) {
    float l = lp[st];
    l += __shfl_xor(l, 16, 64);
    l += __shfl_xor(l, 32, 64);
#pragma unroll
    for (int r = 0; r < 4; r++) linv[st][r] = 1.f / __shfl(l, lq * 4 + r, 64);
  }
  float s_acc = 0.f, ss_acc = 0.f;
#pragma unroll
  for (int nt = 0; nt < 4; nt++)
#pragma unroll
    for (int r = 0; r < 4; r++) {
      size_t a = ((size_t)bh * TQ_ + q0 + lq * 4 + r) * 64 + nt * 16 + ln;
      float val = O[0][nt][r] * linv[0][r] - c * O[1][nt][r] * linv[1][r];
      s_acc += val;
      ss_acc += val * val;
      y[a] = to_bf16(val);
    }
  // GroupNorm partial stats: wave-reduce, one atomic pair per wave
#pragma unroll
  for (int m = 1; m < 64; m <<= 1) {
    s_acc += __shfl_xor(s_acc, m, 64);
    ss_acc += __shfl_xor(ss_acc, m, 64);
  }
  if (lane == 0) {
    atomicAdd(&part[bh * 2], s_acc);
    atomicAdd(&part[bh * 2 + 1], ss_acc);
  }
}

// ---------------- GroupNorm apply (stats from part) + layout to (B,TQ,D) bf16 ----------------
__global__ __launch_bounds__(256) void k_gn_apply(const bf16_t* __restrict__ y,
                                                  const float* __restrict__ part,
                                                  const float* __restrict__ gw,
                                                  const float* __restrict__ gb,
                                                  bf16_t* __restrict__ yn) {
  int idx = blockIdx.x * 256 + threadIdx.x;
  int i = idx * 8;
  int bh = i >> 16;
  int h = bh & 15, b = bh >> 4;
  float S = part[bh * 2], SS = part[bh * 2 + 1];
  float mean = S * (1.f / 65536.f);
  float var = SS * (1.f / 65536.f) - mean * mean;
  float rstd = rsqrtf(var + 1e-5f);
  bf16x8 a = *(const bf16x8*)(y + i);
  int rem = i & 65535;
  int t = rem >> 6, d = rem & 63;
  bf16x8 o;
#pragma unroll
  for (int j = 0; j < 8; j++) {
    float f = (bf2f(a[j]) - mean) * rstd * gw[h * 64 + d + j] + gb[h * 64 + d + j];
    o[j] = to_bf16(f);
  }
  *(bf16x8*)(yn + ((size_t)(b * 1024 + t)) * 1024 + h * 64 + d) = o;
}

extern "C" void kernel_launch(void* const* d_in, const int* in_sizes, int n_in,
                              void* d_out, int out_size, void* d_ws, size_t ws_size,
                              hipStream_t stream) {
  const float* x_q = (const float*)d_in[0];
  const float* x_kv = (const float*)d_in[1];
  const float* Wq = (const float*)d_in[2];
  const float* Wkv = (const float*)d_in[3];
  const float* Wc = (const float*)d_in[4];
  const float* qn1 = (const float*)d_in[5];
  const float* kn1 = (const float*)d_in[6];
  const float* qn2 = (const float*)d_in[7];
  const float* kn2 = (const float*)d_in[8];
  const float* gn_w = (const float*)d_in[9];
  const float* gn_b = (const float*)d_in[10];
  const float* lmb = (const float*)d_in[11];

  const size_t MB = (size_t)1 << 20;
  char* ws = (char*)d_ws;
  bf16_t* xq_bf = (bf16_t*)(ws + 0 * MB);
  bf16_t* xkv_bf = (bf16_t*)(ws + 8 * MB);
  bf16_t* Wqt = (bf16_t*)(ws + 16 * MB);
  bf16_t* Wkvt = (bf16_t*)(ws + 20 * MB);
  bf16_t* Wct = (bf16_t*)(ws + 26 * MB);
  bf16_t* q12 = (bf16_t*)(ws + 28 * MB);
  bf16_t* k1h = (bf16_t*)(ws + 44 * MB);
  bf16_t* k2h = (bf16_t*)(ws + 52 * MB);
  bf16_t* vt = (bf16_t*)(ws + 60 * MB);
  bf16_t* y = (bf16_t*)(ws + 68 * MB);
  bf16_t* yn = (bf16_t*)(ws + 76 * MB);
  float* part = (float*)(ws + 84 * MB);  // 128 floats

  k_prep<<<14336, 256, 0, stream>>>(x_q, x_kv, Wq, Wkv, Wc, xq_bf, xkv_bf, Wqt, Wkvt, Wct,
                                    part);
  k_gemm_qkv<<<1280, 256, 0, stream>>>(xq_bf, xkv_bf, Wqt, Wkvt, kn1, kn2, q12, k1h, k2h,
                                       vt);
  k_attn2<<<dim3(64, 16), 256, 0, stream>>>(q12, k1h, k2h, vt, qn1, qn2, lmb, y, part);
  k_gn_apply<<<2048, 256, 0, stream>>>(y, part, gn_w, gn_b, yn);
  k_gemm64<<<512, 256, 0, stream>>>(yn, Wct, (float*)d_out, 1024, 1024);
}

// Round 6
// 238.317 us; speedup vs baseline: 1.7322x; 1.1271x over previous
//
#include <hip/hip_runtime.h>
#include <cstdint>
#include <cstddef>

#define B_ 4
#define TQ_ 1024
#define TKV_ 1024
#define D_ 1024
#define H_ 16
#define HD_ 64

typedef __bf16 bf16_t;
typedef bf16_t bf16x4 __attribute__((ext_vector_type(4)));
typedef bf16_t bf16x8 __attribute__((ext_vector_type(8)));
typedef float f32x4 __attribute__((ext_vector_type(4)));

#if __has_builtin(__builtin_amdgcn_exp2f)
#define EXP2F __builtin_amdgcn_exp2f
#else
#define EXP2F exp2f
#endif

__device__ __forceinline__ bf16_t to_bf16(float f) {
  uint32_t u = __builtin_bit_cast(uint32_t, f);
  u += 0x7fffu + ((u >> 16) & 1u);
  uint16_t h = (uint16_t)(u >> 16);
  return __builtin_bit_cast(bf16_t, h);
}
__device__ __forceinline__ float bf2f(bf16_t b) {
  uint32_t u = ((uint32_t)__builtin_bit_cast(uint16_t, b)) << 16;
  return __builtin_bit_cast(float, u);
}
// pack two fp32 -> two bf16 (truncation) in ONE v_perm_b32
__device__ __forceinline__ uint32_t pack_bf16_trunc(float lo, float hi) {
  return __builtin_amdgcn_perm(__builtin_bit_cast(uint32_t, hi),
                               __builtin_bit_cast(uint32_t, lo), 0x07060302u);
}
__device__ __forceinline__ void gload_lds16(const void* g, void* l) {
  __builtin_amdgcn_global_load_lds((const __attribute__((address_space(1))) void*)g,
                                   (__attribute__((address_space(3))) void*)l, 16, 0, 0);
}

// ---------------- prep: f2b of activations + weight transpose + zero(part) ----------------
__global__ __launch_bounds__(256) void k_prep(const float* __restrict__ xq,
                                              const float* __restrict__ xkv,
                                              const float* __restrict__ Wq,
                                              const float* __restrict__ Wkv,
                                              const float* __restrict__ Wc,
                                              bf16_t* __restrict__ oq,
                                              bf16_t* __restrict__ okv,
                                              bf16_t* __restrict__ Wqt,
                                              bf16_t* __restrict__ Wkvt,
                                              bf16_t* __restrict__ Wct,
                                              float* __restrict__ part) {
  int blk = blockIdx.x;
  if (blk == 0 && threadIdx.x < 128) part[threadIdx.x] = 0.f;
  if (blk < 8192) {
    const float* in = (blk < 4096) ? xq : xkv;
    bf16_t* out = (blk < 4096) ? oq : okv;
    int i = (blk & 4095) * 256 + threadIdx.x;
    float4 v = ((const float4*)in)[i];
    bf16x4 o = {to_bf16(v.x), to_bf16(v.y), to_bf16(v.z), to_bf16(v.w)};
    *(bf16x4*)(out + (size_t)i * 4) = o;
  } else {
    __shared__ float tile[32][33];
    int t = blk - 8192;             // 0..6143
    int x = t % 192, yb = t / 192;  // yb 0..31
    const float* in;
    bf16_t* out;
    int C, c0;
    if (x < 64) { in = Wq; out = Wqt; C = 2048; c0 = x * 32; }
    else if (x < 160) { in = Wkv; out = Wkvt; C = 3072; c0 = (x - 64) * 32; }
    else { in = Wc; out = Wct; C = 1024; c0 = (x - 160) * 32; }
    int r0 = yb * 32;
    int tx = threadIdx.x & 31, ty = threadIdx.x >> 5;
#pragma unroll
    for (int i = 0; i < 4; i++)
      tile[ty + i * 8][tx] = in[(size_t)(r0 + ty + i * 8) * C + c0 + tx];
    __syncthreads();
#pragma unroll
    for (int i = 0; i < 4; i++) {
      int rr = ty + i * 8;
      out[(size_t)(c0 + rr) * 1024 + r0 + tx] = to_bf16(tile[tx][rr]);
    }
  }
}

// ---------------- merged Q+KV projection GEMM, XCD-supertiled ----------------
// K-RMSNorm fused into k1/k2 epilogue; V written TRANSPOSED + within-32 t-granule
// permuted (t' = lq*8 + h*4 + r), so attention V-frags are single b128 LDS reads.
__global__ __launch_bounds__(256, 2) void k_gemm_qkv(const bf16_t* __restrict__ xq,
                                                     const bf16_t* __restrict__ xkv,
                                                     const bf16_t* __restrict__ Wqt,
                                                     const bf16_t* __restrict__ Wkvt,
                                                     const float* __restrict__ kn1,
                                                     const float* __restrict__ kn2,
                                                     bf16_t* __restrict__ q12,
                                                     bf16_t* __restrict__ k1h,
                                                     bf16_t* __restrict__ k2h,
                                                     bf16_t* __restrict__ vt) {
  __shared__ bf16_t As[128 * 32];
  __shared__ bf16_t Bs[128 * 32];
  const int tid = threadIdx.x;
  const int wave = tid >> 6, lane = tid & 63;
  const int ln = lane & 15, lq = lane >> 4;

  const int fid = blockIdx.x;
  const int xcd = fid & 7, l = fid >> 3;  // l in [0,160)
  bool isq;
  int xb, yb;
  if (l < 64) {
    isq = true;
    xb = (xcd & 3) * 4 + (l & 3);
    yb = (xcd >> 2) * 16 + (l >> 2);
  } else {
    isq = false;
    int l2 = l - 64;
    xb = (xcd & 3) * 6 + l2 % 6;
    yb = (xcd >> 2) * 16 + l2 / 6;
  }
  const bf16_t* A = isq ? xq : xkv;
  const bf16_t* Bt = isq ? Wqt : Wkvt;
  const int n0 = xb * 128, m0 = yb * 128;
  const int wm = (wave >> 1) * 64, wn = (wave & 1) * 64;
  f32x4 acc[4][4];
#pragma unroll
  for (int i = 0; i < 4; i++)
#pragma unroll
    for (int j = 0; j < 4; j++) acc[i][j] = (f32x4){0.f, 0.f, 0.f, 0.f};

  for (int k0 = 0; k0 < 1024; k0 += 32) {
#pragma unroll
    for (int rnd = 0; rnd < 2; rnd++) {
      int c = rnd * 256 + tid;
      int row = c >> 2, col = (c & 3) * 8;
      int ldsoff = (rnd * 256 + wave * 64) * 16;
      gload_lds16(A + (size_t)(m0 + row) * 1024 + k0 + col, (char*)As + ldsoff);
      gload_lds16(Bt + (size_t)(n0 + row) * 1024 + k0 + col, (char*)Bs + ldsoff);
    }
    asm volatile("s_waitcnt vmcnt(0)" ::: "memory");
    __syncthreads();
    bf16x8 af[4], bfr[4];
#pragma unroll
    for (int i = 0; i < 4; i++) {
      af[i] = *(const bf16x8*)(As + (wm + i * 16 + ln) * 32 + lq * 8);
      bfr[i] = *(const bf16x8*)(Bs + (wn + i * 16 + ln) * 32 + lq * 8);
    }
#pragma unroll
    for (int i = 0; i < 4; i++)
#pragma unroll
      for (int j = 0; j < 4; j++)
        acc[i][j] = __builtin_amdgcn_mfma_f32_16x16x32_bf16(af[i], bfr[j], acc[i][j], 0, 0, 0);
    __syncthreads();
  }

  if (isq) {
#pragma unroll
    for (int i = 0; i < 4; i++)
#pragma unroll
      for (int j = 0; j < 4; j++)
#pragma unroll
        for (int r = 0; r < 4; r++) {
          int row = m0 + wm + i * 16 + lq * 4 + r;
          int col = n0 + wn + j * 16 + ln;
          q12[(size_t)row * 2048 + col] = to_bf16(acc[i][j][r]);
        }
  } else {
    const int col0 = n0 + wn;
    const int part3 = col0 >> 10;  // 0:k1, 1:k2, 2:v
    const int h = (col0 >> 6) & 15;
    const int b = m0 >> 10;
    const int bh = b * 16 + h;
    if (part3 < 2) {
      const float* kn = part3 ? kn2 : kn1;
      bf16_t* dst = part3 ? k2h : k1h;
      float kw[4];
#pragma unroll
      for (int j = 0; j < 4; j++) kw[j] = kn[j * 16 + ln];
#pragma unroll
      for (int i = 0; i < 4; i++)
#pragma unroll
        for (int r = 0; r < 4; r++) {
          float ss = 0.f;
#pragma unroll
          for (int j = 0; j < 4; j++) ss += acc[i][j][r] * acc[i][j][r];
          ss += __shfl_xor(ss, 1, 64);
          ss += __shfl_xor(ss, 2, 64);
          ss += __shfl_xor(ss, 4, 64);
          ss += __shfl_xor(ss, 8, 64);
          float rstd = rsqrtf(ss * (1.f / 64.f) + 1e-5f);
          int m = m0 + wm + i * 16 + lq * 4 + r;
          int t = m & 1023;
          size_t base = ((size_t)bh * 1024 + t) * 64;
#pragma unroll
          for (int j = 0; j < 4; j++)
            dst[base + j * 16 + ln] = to_bf16(acc[i][j][r] * rstd * kw[j]);
        }
    } else {
      // V: vt'[bh][d][t'], t' permuted within each 32-block:
      // kv = h*16 + lqw*4 + r  ->  t' = lqw*8 + h*4 + r
      bf16_t* obase = vt + (size_t)bh * 65536;
#pragma unroll
      for (int i = 0; i < 4; i++) {
        int t0 = (m0 & 1023) + wm + i * 16 + lq * 4;
        int tp = (t0 & ~31) | (((t0 >> 2) & 3) << 3) | (((t0 >> 4) & 1) << 2);
#pragma unroll
        for (int j = 0; j < 4; j++) {
          bf16x4 pv;
#pragma unroll
          for (int r = 0; r < 4; r++) pv[r] = to_bf16(acc[i][j][r]);
          *(bf16x4*)(obase + (size_t)(j * 16 + ln) * 1024 + tp) = pv;
        }
      }
    }
  }
}

// ---------------- bf16 GEMM 128x64 tile (fp32 out), XCD-supertiled ----------------
__global__ __launch_bounds__(256, 2) void k_gemm64(const bf16_t* __restrict__ A,
                                                   const bf16_t* __restrict__ Bt,
                                                   float* __restrict__ C, int N, int K) {
  __shared__ bf16_t As[128 * 32];
  __shared__ bf16_t Bs[64 * 32];
  const int tid = threadIdx.x;
  const int wave = tid >> 6, lane = tid & 63;
  const int ln = lane & 15, lq = lane >> 4;
  const int fid = blockIdx.x;             // flat 512
  const int xcd = fid & 7, l = fid >> 3;  // 0..63
  const int lx = l & 1, ly = (l >> 1) & 15, yh = l >> 5;
  const int n0 = (xcd * 2 + lx) * 64;
  const int m0 = (yh * 16 + ly) * 128;
  const int wm = wave * 32;
  f32x4 acc[2][4];
#pragma unroll
  for (int i = 0; i < 2; i++)
#pragma unroll
    for (int j = 0; j < 4; j++) acc[i][j] = (f32x4){0.f, 0.f, 0.f, 0.f};

  for (int k0 = 0; k0 < K; k0 += 32) {
#pragma unroll
    for (int rnd = 0; rnd < 2; rnd++) {
      int c = rnd * 256 + tid;
      int row = c >> 2, col = (c & 3) * 8;
      int ldsoff = (rnd * 256 + wave * 64) * 16;
      gload_lds16(A + (size_t)(m0 + row) * K + k0 + col, (char*)As + ldsoff);
    }
    {
      int row = tid >> 2, col = (tid & 3) * 8;
      int ldsoff = (wave * 64) * 16;
      gload_lds16(Bt + (size_t)(n0 + row) * K + k0 + col, (char*)Bs + ldsoff);
    }
    asm volatile("s_waitcnt vmcnt(0)" ::: "memory");
    __syncthreads();
    bf16x8 af[2], bfr[4];
#pragma unroll
    for (int i = 0; i < 2; i++)
      af[i] = *(const bf16x8*)(As + (wm + i * 16 + ln) * 32 + lq * 8);
#pragma unroll
    for (int j = 0; j < 4; j++)
      bfr[j] = *(const bf16x8*)(Bs + (j * 16 + ln) * 32 + lq * 8);
#pragma unroll
    for (int i = 0; i < 2; i++)
#pragma unroll
      for (int j = 0; j < 4; j++)
        acc[i][j] = __builtin_amdgcn_mfma_f32_16x16x32_bf16(af[i], bfr[j], acc[i][j], 0, 0, 0);
    __syncthreads();
  }
#pragma unroll
  for (int i = 0; i < 2; i++)
#pragma unroll
    for (int j = 0; j < 4; j++)
#pragma unroll
      for (int r = 0; r < 4; r++) {
        int row = m0 + wm + i * 16 + lq * 4 + r;
        int col = n0 + j * 16 + ln;
        C[(size_t)row * N + col] = acc[i][j][r];
      }
}

// ---------------- fused dual-stream flash attention + GN partial stats ----------------
// grid (64=bh, 8=qblock); block 256 = 4 waves x 32 q-rows (128 q/block).
// V-frags: single b128 per (u,nt), loaded ONCE per chunk (shared by both streams).
// K-frags amortized over mt=2 q-tiles. One atomic pair per block for GN stats.
__global__ __launch_bounds__(256, 2) void k_attn2(const bf16_t* __restrict__ q12,
                                                  const bf16_t* __restrict__ k1h,
                                                  const bf16_t* __restrict__ k2h,
                                                  const bf16_t* __restrict__ vt,
                                                  const float* __restrict__ qn1,
                                                  const float* __restrict__ qn2,
                                                  const float* __restrict__ lmb,
                                                  bf16_t* __restrict__ y,
                                                  float* __restrict__ part) {
  __shared__ bf16_t Ks[2][4096];  // [kv][d] XOR-swizzled 16B granules
  __shared__ bf16_t Vs[4096];     // [d][t'] XOR-swizzled 16B granules
  __shared__ float red[8];
  const int tid = threadIdx.x;
  const int wave = tid >> 6, lane = tid & 63;
  const int ln = lane & 15, lq = lane >> 4;
  const int swz = ln & 7;
  const int bh = blockIdx.x;
  const int b = bh >> 4, h = bh & 15;
  const int q0 = blockIdx.y * 128 + wave * 32;
  const bf16_t* kb[2] = {k1h + (size_t)bh * 65536, k2h + (size_t)bh * 65536};
  const bf16_t* vb = vt + (size_t)bh * 65536;

  // ---- Q load (2 streams x 2 m-tiles) + fused RMSNorm * qn * (0.125*log2e) ----
  bf16x8 qf[2][2][2];  // [stream][mt][ks]
#pragma unroll
  for (int st = 0; st < 2; st++)
#pragma unroll
    for (int mt = 0; mt < 2; mt++)
#pragma unroll
      for (int ks = 0; ks < 2; ks++)
        qf[st][mt][ks] = *(const bf16x8*)(q12 + (size_t)(b * 1024 + q0 + mt * 16 + ln) * 2048 +
                                          st * 1024 + h * 64 + ks * 32 + lq * 8);
#pragma unroll
  for (int st = 0; st < 2; st++)
#pragma unroll
    for (int mt = 0; mt < 2; mt++) {
      const float* qn = st ? qn2 : qn1;
      float ssq = 0.f;
#pragma unroll
      for (int ks = 0; ks < 2; ks++)
#pragma unroll
        for (int j = 0; j < 8; j++) {
          float v = bf2f(qf[st][mt][ks][j]);
          ssq += v * v;
        }
      ssq += __shfl_xor(ssq, 16, 64);
      ssq += __shfl_xor(ssq, 32, 64);
      float rr = rsqrtf(ssq * (1.f / 64.f) + 1e-5f) * (0.125f * 1.44269504f);
#pragma unroll
      for (int ks = 0; ks < 2; ks++)
#pragma unroll
        for (int j = 0; j < 8; j++)
          qf[st][mt][ks][j] = to_bf16(bf2f(qf[st][mt][ks][j]) * rr * qn[ks * 32 + lq * 8 + j]);
    }

  f32x4 O[2][2][4];  // [stream][mt][nt]
  float lp[2][2] = {{0.f, 0.f}, {0.f, 0.f}};
#pragma unroll
  for (int st = 0; st < 2; st++)
#pragma unroll
    for (int mt = 0; mt < 2; mt++)
#pragma unroll
      for (int nt = 0; nt < 4; nt++) O[st][mt][nt] = (f32x4){0.f, 0.f, 0.f, 0.f};

  for (int kv0 = 0; kv0 < TKV_; kv0 += 64) {
    __syncthreads();
#pragma unroll
    for (int r = 0; r < 6; r++) {
      int a = r >> 1, r2 = r & 1;
      int g = r2 * 256 + tid;
      int row = g >> 3;
      int blk = (g & 7) ^ (row & 7);
      const bf16_t* src = (a < 2) ? (kb[a] + (size_t)(kv0 + row) * 64 + blk * 8)
                                  : (vb + (size_t)row * 1024 + kv0 + blk * 8);
      char* dst = (a < 2) ? ((char*)Ks + a * 8192) : (char*)Vs;
      gload_lds16(src, dst + (r2 * 256 + wave * 64) * 16);
    }
    asm volatile("s_waitcnt vmcnt(0)" ::: "memory");
    __syncthreads();

    // V B-frags: ONE b128 per (u,nt), shared by both streams and both m-tiles
    bf16x8 vf[2][4];
#pragma unroll
    for (int u = 0; u < 2; u++)
#pragma unroll
      for (int nt = 0; nt < 4; nt++)
        vf[u][nt] = *(const bf16x8*)(Vs + ((nt * 16 + ln) * 8 + ((u * 4 + lq) ^ swz)) * 8);

#pragma unroll
    for (int st = 0; st < 2; st++) {
      bf16x8 kf[2][4];
#pragma unroll
      for (int ks = 0; ks < 2; ks++)
#pragma unroll
        for (int t = 0; t < 4; t++)
          kf[ks][t] = *(const bf16x8*)(&Ks[st][((t * 16 + ln) * 8 + ((4 * ks + lq) ^ swz)) * 8]);
#pragma unroll
      for (int mt = 0; mt < 2; mt++) {
        f32x4 s[4];
#pragma unroll
        for (int t = 0; t < 4; t++) s[t] = (f32x4){0.f, 0.f, 0.f, 0.f};
#pragma unroll
        for (int ks = 0; ks < 2; ks++)
#pragma unroll
          for (int t = 0; t < 4; t++)
            s[t] = __builtin_amdgcn_mfma_f32_16x16x32_bf16(kf[ks][t], qf[st][mt][ks], s[t], 0, 0, 0);
        uint32_t pfu[2][4];
        float l = 0.f;
#pragma unroll
        for (int t = 0; t < 4; t++) {
          float e0 = EXP2F(s[t][0]), e1 = EXP2F(s[t][1]);
          float e2 = EXP2F(s[t][2]), e3 = EXP2F(s[t][3]);
          l += (e0 + e1) + (e2 + e3);
          pfu[t >> 1][(t & 1) * 2] = pack_bf16_trunc(e0, e1);
          pfu[t >> 1][(t & 1) * 2 + 1] = pack_bf16_trunc(e2, e3);
        }
        lp[st][mt] += l;
#pragma unroll
        for (int u = 0; u < 2; u++) {
          bf16x8 pf = __builtin_bit_cast(bf16x8, *(uint4*)pfu[u]);
#pragma unroll
          for (int nt = 0; nt < 4; nt++)
            O[st][mt][nt] =
                __builtin_amdgcn_mfma_f32_16x16x32_bf16(pf, vf[u][nt], O[st][mt][nt], 0, 0, 0);
        }
      }
    }
  }

  float c = log1pf(__expf(lmb[h]));
  float s_acc = 0.f, ss_acc = 0.f;
#pragma unroll
  for (int mt = 0; mt < 2; mt++) {
    float linv[2][4];
#pragma unroll
    for (int st = 0; st < 2; st++) {
      float l = lp[st][mt];
      l += __shfl_xor(l, 16, 64);
      l += __shfl_xor(l, 32, 64);
#pragma unroll
      for (int r = 0; r < 4; r++) linv[st][r] = 1.f / __shfl(l, lq * 4 + r, 64);
    }
#pragma unroll
    for (int nt = 0; nt < 4; nt++)
#pragma unroll
      for (int r = 0; r < 4; r++) {
        size_t a = ((size_t)bh * TQ_ + q0 + mt * 16 + lq * 4 + r) * 64 + nt * 16 + ln;
        float val = O[0][mt][nt][r] * linv[0][r] - c * O[1][mt][nt][r] * linv[1][r];
        s_acc += val;
        ss_acc += val * val;
        y[a] = to_bf16(val);
      }
  }
  // GN partial stats: wave-reduce -> LDS -> one atomic pair per block
#pragma unroll
  for (int m = 1; m < 64; m <<= 1) {
    s_acc += __shfl_xor(s_acc, m, 64);
    ss_acc += __shfl_xor(ss_acc, m, 64);
  }
  if (lane == 0) {
    red[wave] = s_acc;
    red[4 + wave] = ss_acc;
  }
  __syncthreads();
  if (tid == 0) {
    atomicAdd(&part[bh * 2], red[0] + red[1] + red[2] + red[3]);
    atomicAdd(&part[bh * 2 + 1], red[4] + red[5] + red[6] + red[7]);
  }
}

// ---------------- GroupNorm apply (stats from part) + layout to (B,TQ,D) bf16 ----------------
__global__ __launch_bounds__(256) void k_gn_apply(const bf16_t* __restrict__ y,
                                                  const float* __restrict__ part,
                                                  const float* __restrict__ gw,
                                                  const float* __restrict__ gb,
                                                  bf16_t* __restrict__ yn) {
  int idx = blockIdx.x * 256 + threadIdx.x;
  int i = idx * 8;
  int bh = i >> 16;
  int h = bh & 15, b = bh >> 4;
  float S = part[bh * 2], SS = part[bh * 2 + 1];
  float mean = S * (1.f / 65536.f);
  float var = SS * (1.f / 65536.f) - mean * mean;
  float rstd = rsqrtf(var + 1e-5f);
  bf16x8 a = *(const bf16x8*)(y + i);
  int rem = i & 65535;
  int t = rem >> 6, d = rem & 63;
  bf16x8 o;
#pragma unroll
  for (int j = 0; j < 8; j++) {
    float f = (bf2f(a[j]) - mean) * rstd * gw[h * 64 + d + j] + gb[h * 64 + d + j];
    o[j] = to_bf16(f);
  }
  *(bf16x8*)(yn + ((size_t)(b * 1024 + t)) * 1024 + h * 64 + d) = o;
}

extern "C" void kernel_launch(void* const* d_in, const int* in_sizes, int n_in,
                              void* d_out, int out_size, void* d_ws, size_t ws_size,
                              hipStream_t stream) {
  const float* x_q = (const float*)d_in[0];
  const float* x_kv = (const float*)d_in[1];
  const float* Wq = (const float*)d_in[2];
  const float* Wkv = (const float*)d_in[3];
  const float* Wc = (const float*)d_in[4];
  const float* qn1 = (const float*)d_in[5];
  const float* kn1 = (const float*)d_in[6];
  const float* qn2 = (const float*)d_in[7];
  const float* kn2 = (const float*)d_in[8];
  const float* gn_w = (const float*)d_in[9];
  const float* gn_b = (const float*)d_in[10];
  const float* lmb = (const float*)d_in[11];

  const size_t MB = (size_t)1 << 20;
  char* ws = (char*)d_ws;
  bf16_t* xq_bf = (bf16_t*)(ws + 0 * MB);
  bf16_t* xkv_bf = (bf16_t*)(ws + 8 * MB);
  bf16_t* Wqt = (bf16_t*)(ws + 16 * MB);
  bf16_t* Wkvt = (bf16_t*)(ws + 20 * MB);
  bf16_t* Wct = (bf16_t*)(ws + 26 * MB);
  bf16_t* q12 = (bf16_t*)(ws + 28 * MB);
  bf16_t* k1h = (bf16_t*)(ws + 44 * MB);
  bf16_t* k2h = (bf16_t*)(ws + 52 * MB);
  bf16_t* vt = (bf16_t*)(ws + 60 * MB);
  bf16_t* y = (bf16_t*)(ws + 68 * MB);
  bf16_t* yn = (bf16_t*)(ws + 76 * MB);
  float* part = (float*)(ws + 84 * MB);  // 128 floats

  k_prep<<<14336, 256, 0, stream>>>(x_q, x_kv, Wq, Wkv, Wc, xq_bf, xkv_bf, Wqt, Wkvt, Wct,
                                    part);
  k_gemm_qkv<<<1280, 256, 0, stream>>>(xq_bf, xkv_bf, Wqt, Wkvt, kn1, kn2, q12, k1h, k2h,
                                       vt);
  k_attn2<<<dim3(64, 8), 256, 0, stream>>>(q12, k1h, k2h, vt, qn1, qn2, lmb, y, part);
  k_gn_apply<<<2048, 256, 0, stream>>>(y, part, gn_w, gn_b, yn);
  k_gemm64<<<512, 256, 0, stream>>>(yn, Wct, (float*)d_out, 1024, 1024);
}